// Round 6
// baseline (317.276 us; speedup 1.0000x reference)
//
#include <hip/hip_runtime.h>
#include <stdint.h>

// Problem constants
#define NN 16384                  // sampled points per batch (h*w)
#define HW 65536                  // H*W
#define OUT_HALF (2 * NN * 128)   // one tuple element, flat floats
// MLP: 67 -> 64 -> 64 -> 128 (BN folded), maxpool over K=32 neighbors.
//
// One wave = TWO points, software-pipelined (T14 async-stage):
//   gather(p0)->regs ; write tile(p0) ; ISSUE gather(p1)->regs ;
//   compute(p0) [hides p1's gather latency] ; write tile(p1) ; compute(p1).
// 32 neighbors = M rows of 16x16x32 bf16 MFMAs; fp32 accuracy via hi/lo bf16
// split, 3 passes: ah*wh + al*wh + ah*wl.
// Waves fully independent (private LDS tile) -> NO __syncthreads; intra-wave
// cross-lane LDS ordering via s_waitcnt lgkmcnt(0) + sched_barrier (rule #18).
// LDS = 4 waves x [32][64] f32 XOR-swizzled = exactly 32 KiB.
// Round-4 lesson: forcing min-waves via __launch_bounds__(256,5) caused 90 MB
// of scratch spill; plain (256) -> no spill.
// XCD swizzle (T1): grid 4096 %8==0; contiguous 512-block chunk per XCD.
//
// Fragment maps (gfx950 16x16x32 bf16, m89-verified):
//   A: row = lane&15, k = 8*(lane>>4)+e ;  B: col = lane&15, same k
//   C/D: col = lane&15, row = 4*(lane>>4)+reg

typedef __attribute__((ext_vector_type(8))) short bf16x8;
typedef __attribute__((ext_vector_type(4))) float f32x4;

// ws layout, uint16 units:
#define WS_L0H 0
#define WS_L0L 6144
#define WS_L1H 12288
#define WS_L1L 16384
#define WS_L2H 20480
#define WS_L2L 28672
#define WS_BIAS 36864

__device__ inline uint16_t f32_to_bf16_rne(float x) {
    uint32_t u = __float_as_uint(x);
    uint32_t r = (u + 0x7FFFu + ((u >> 16) & 1u)) >> 16;
    return (uint16_t)r;
}
__device__ inline float bf16_hi_f32(uint16_t h) {
    return __uint_as_float(((uint32_t)h) << 16);
}
__device__ inline void split2(float v, uint16_t* hi, uint16_t* lo) {
    uint16_t h = f32_to_bf16_rne(v);
    *hi = h;
    *lo = f32_to_bf16_rne(v - bf16_hi_f32(h));
}

// ---------------- weight prep (runs once per launch, tiny) ----------------
__global__ void prep_weights(
    const float* __restrict__ W0, const float* __restrict__ b0,
    const float* __restrict__ g0, const float* __restrict__ be0,
    const float* __restrict__ W1, const float* __restrict__ b1,
    const float* __restrict__ g1, const float* __restrict__ be1,
    const float* __restrict__ W2, const float* __restrict__ b2,
    const float* __restrict__ g2, const float* __restrict__ be2,
    uint16_t* __restrict__ ws)
{
    const int tid = blockIdx.x * blockDim.x + threadIdx.x;
    const int nth = gridDim.x * blockDim.x;

    // L0: [3 kt][4 nt][64 lane][8 e]; k 0..63 -> W0 row 3+k, 64..66 -> row k-64
    for (int i = tid; i < 6144; i += nth) {
        int e = i & 7, lane = (i >> 3) & 63, nt = (i >> 9) & 3, kt = i >> 11;
        int k = kt * 32 + 8 * (lane >> 4) + e;
        int n = nt * 16 + (lane & 15);
        float v = 0.f;
        if (k < 64)       v = W0[(3 + k) * 64 + n] * g0[n];
        else if (k < 67)  v = W0[(k - 64) * 64 + n] * g0[n];
        uint16_t hi, lo; split2(v, &hi, &lo);
        ws[WS_L0H + i] = hi; ws[WS_L0L + i] = lo;
    }
    for (int i = tid; i < 4096; i += nth) {
        int e = i & 7, lane = (i >> 3) & 63, nt = (i >> 9) & 3, kt = i >> 11;
        int k = kt * 32 + 8 * (lane >> 4) + e;
        int n = nt * 16 + (lane & 15);
        float v = W1[k * 64 + n] * g1[n];
        uint16_t hi, lo; split2(v, &hi, &lo);
        ws[WS_L1H + i] = hi; ws[WS_L1L + i] = lo;
    }
    for (int i = tid; i < 8192; i += nth) {
        int e = i & 7, lane = (i >> 3) & 63, nt = (i >> 9) & 7, kt = i >> 12;
        int k = kt * 32 + 8 * (lane >> 4) + e;
        int n = nt * 16 + (lane & 15);
        float v = W2[k * 128 + n] * g2[n];
        uint16_t hi, lo; split2(v, &hi, &lo);
        ws[WS_L2H + i] = hi; ws[WS_L2L + i] = lo;
    }
    float* bias = (float*)(ws + WS_BIAS);
    for (int i = tid; i < 64; i += nth)  bias[i]       = b0[i] * g0[i] + be0[i];
    for (int i = tid; i < 64; i += nth)  bias[64 + i]  = b1[i] * g1[i] + be1[i];
    for (int i = tid; i < 128; i += nth) bias[128 + i] = b2[i] * g2[i] + be2[i];
}

// ---------------- main kernel helpers ----------------
__device__ inline uint32_t cvt_pk_bf16(float a, float b) {
    uint32_t r;
    asm("v_cvt_pk_bf16_f32 %0, %1, %2" : "=v"(r) : "v"(a), "v"(b));
    return r;
}

union frag_u { uint32_t w[4]; bf16x8 v; };

// split 8 f32 -> hi/lo bf16x8 via packed converts (lo = a - f32(hi), exact)
__device__ inline void split8(const float* f, bf16x8* hi, bf16x8* lo) {
    frag_u H, L;
    #pragma unroll
    for (int p2 = 0; p2 < 4; ++p2) {
        float a = f[2 * p2], b = f[2 * p2 + 1];
        uint32_t h = cvt_pk_bf16(a, b);
        float ha = __uint_as_float(h << 16);
        float hb = __uint_as_float(h & 0xffff0000u);
        uint32_t l = cvt_pk_bf16(a - ha, b - hb);
        H.w[p2] = h; L.w[p2] = l;
    }
    *hi = H.v; *lo = L.v;
}

__device__ inline f32x4 mfma3(bf16x8 ah, bf16x8 al, bf16x8 wh, bf16x8 wl, f32x4 c) {
    c = __builtin_amdgcn_mfma_f32_16x16x32_bf16(ah, wh, c, 0, 0, 0);
    c = __builtin_amdgcn_mfma_f32_16x16x32_bf16(al, wh, c, 0, 0, 0);
    c = __builtin_amdgcn_mfma_f32_16x16x32_bf16(ah, wl, c, 0, 0, 0);
    return c;
}

// swizzled f32 tile [32][64]: elem = row*64 + (col ^ ((row&7)<<2))
__device__ inline void load_frag(const float* tile, int row, int c0, float* f) {
    const int sw = (row & 7) << 2;
    *(float4*)&f[0] = *(const float4*)&tile[row * 64 + (c0 ^ sw)];
    *(float4*)&f[4] = *(const float4*)&tile[row * 64 + ((c0 + 4) ^ sw)];
}

#define WAVE_LDS_FENCE() do { \
    asm volatile("s_waitcnt lgkmcnt(0)" ::: "memory"); \
    __builtin_amdgcn_sched_barrier(0); \
} while (0)

__global__ __launch_bounds__(256)
void pointnet_mfma(
    const float* __restrict__ xyz_proj,      // [B, H*W, 3]
    const float* __restrict__ points_proj,   // [B, H*W, 64]
    const float* __restrict__ xyz_sampled,   // [B, N, 3]
    const int*   __restrict__ nidx,          // [B, N, 32]
    const float* __restrict__ vmask,         // [B, N, 32, 1]
    const uint16_t* __restrict__ wf,
    float* __restrict__ out)
{
    __shared__ float s_feat[4][2048];   // exactly 32 KiB

    // XCD-aware bijective swizzle (grid 4096, 8 XCDs, 512 blocks per XCD)
    const int bid = blockIdx.x;
    const int swz = (bid & 7) * 512 + (bid >> 3);

    const int t     = threadIdx.x & 63;
    const int widx  = threadIdx.x >> 6;
    const int pbase = swz * 8 + widx * 2;     // 2 points per wave, 8 per block
    const int b     = pbase >> 14;             // pair never crosses batch (16384 even)

    float* tile = s_feat[widx];

    const bf16x8* L0h = (const bf16x8*)(wf + WS_L0H);
    const bf16x8* L0l = (const bf16x8*)(wf + WS_L0L);
    const bf16x8* L1h = (const bf16x8*)(wf + WS_L1H);
    const bf16x8* L1l = (const bf16x8*)(wf + WS_L1L);
    const bf16x8* L2h = (const bf16x8*)(wf + WS_L2H);
    const bf16x8* L2l = (const bf16x8*)(wf + WS_L2L);
    const float*  bias = (const float*)(wf + WS_BIAS);

    const int r  = t & 31;
    const int hh = t >> 5;

    // ---- prologue: idx/mask/xyz for BOTH points; gather p0 into regs ----
    const int   idx0 = nidx[(size_t)(pbase + 0) * 32 + r];
    const float m0   = vmask[(size_t)(pbase + 0) * 32 + r];
    const int   idx1 = nidx[(size_t)(pbase + 1) * 32 + r];
    const float m1   = vmask[(size_t)(pbase + 1) * 32 + r];

    float4 pf[8];
    {
        const float* src0 = points_proj + ((size_t)b * HW + idx0) * 64 + hh * 32;
        #pragma unroll
        for (int q = 0; q < 8; ++q) pf[q] = ((const float4*)src0)[q];
    }
    float xd0_0, xd0_1, xd0_2, xd1_0, xd1_1, xd1_2;
    {
        const float* xs0 = xyz_proj + ((size_t)b * HW + idx0) * 3;
        const float* xs1 = xyz_proj + ((size_t)b * HW + idx1) * 3;
        const float* ns0 = xyz_sampled + (size_t)(pbase + 0) * 3;
        const float* ns1 = xyz_sampled + (size_t)(pbase + 1) * 3;
        xd0_0 = xs0[0] * m0 - ns0[0];
        xd0_1 = xs0[1] * m0 - ns0[1];
        xd0_2 = xs0[2] * m0 - ns0[2];
        xd1_0 = xs1[0] * m1 - ns1[0];
        xd1_1 = xs1[1] * m1 - ns1[1];
        xd1_2 = xs1[2] * m1 - ns1[2];
    }
    const float* src1 = points_proj + ((size_t)b * HW + idx1) * 64 + hh * 32;

    #pragma unroll 1
    for (int it = 0; it < 2; ++it) {
        // drain prior iteration's ds_reads before overwriting the tile
        WAVE_LDS_FENCE();

        const float mcur = it ? m1 : m0;
        {
            const int sw = (r & 7) << 2;
            #pragma unroll
            for (int q = 0; q < 8; ++q) {
                float4 v = pf[q];
                v.x *= mcur; v.y *= mcur; v.z *= mcur; v.w *= mcur;
                const int c0 = hh * 32 + 4 * q;
                *(float4*)&tile[r * 64 + (c0 ^ sw)] = v;
            }
        }
        // T14: issue next point's gather NOW; latency hides under compute(p0)
        if (it == 0) {
            #pragma unroll
            for (int q = 0; q < 8; ++q) pf[q] = ((const float4*)src1)[q];
        }
        const float xdA = it ? xd1_0 : xd0_0;
        const float xdB = it ? xd1_1 : xd0_1;
        const float xdC = it ? xd1_2 : xd0_2;
        const int p = pbase + it;

        WAVE_LDS_FENCE();

        // ---- layer 0: K = 64 (pts) + 3 (xyz) -> 64 ----
        f32x4 acc0[2][4] = {};
        #pragma unroll
        for (int kt = 0; kt < 2; ++kt) {
            bf16x8 ah[2], al[2];
            #pragma unroll
            for (int mt = 0; mt < 2; ++mt) {
                float f[8];
                load_frag(tile, mt * 16 + (t & 15), kt * 32 + 8 * (t >> 4), f);
                split8(f, &ah[mt], &al[mt]);
            }
            #pragma unroll
            for (int nt = 0; nt < 4; ++nt) {
                bf16x8 wh = L0h[(kt * 4 + nt) * 64 + t];
                bf16x8 wl = L0l[(kt * 4 + nt) * 64 + t];
                #pragma unroll
                for (int mt = 0; mt < 2; ++mt)
                    acc0[mt][nt] = mfma3(ah[mt], al[mt], wh, wl, acc0[mt][nt]);
            }
        }
        {   // xyz k-step (kt=2): lanes g==0 carry e=0..2; rest zero
            const int srow = t & 15;
            float a0 = __shfl(xdA, srow),      a1 = __shfl(xdB, srow),      a2 = __shfl(xdC, srow);
            float c0 = __shfl(xdA, srow + 16), c1 = __shfl(xdB, srow + 16), c2 = __shfl(xdC, srow + 16);
            const bool g0 = (t >> 4) == 0;
            float f0[8] = { g0 ? a0 : 0.f, g0 ? a1 : 0.f, g0 ? a2 : 0.f, 0.f, 0.f, 0.f, 0.f, 0.f };
            float f1[8] = { g0 ? c0 : 0.f, g0 ? c1 : 0.f, g0 ? c2 : 0.f, 0.f, 0.f, 0.f, 0.f, 0.f };
            bf16x8 ah[2], al[2];
            split8(f0, &ah[0], &al[0]);
            split8(f1, &ah[1], &al[1]);
            #pragma unroll
            for (int nt = 0; nt < 4; ++nt) {
                bf16x8 wh = L0h[(8 + nt) * 64 + t];
                bf16x8 wl = L0l[(8 + nt) * 64 + t];
                #pragma unroll
                for (int mt = 0; mt < 2; ++mt)
                    acc0[mt][nt] = mfma3(ah[mt], al[mt], wh, wl, acc0[mt][nt]);
            }
        }
        {   // bias + relu -> writeback (swizzled)
            float bb[4];
            #pragma unroll
            for (int nt = 0; nt < 4; ++nt) bb[nt] = bias[nt * 16 + (t & 15)];
            #pragma unroll
            for (int mt = 0; mt < 2; ++mt)
                #pragma unroll
                for (int nt = 0; nt < 4; ++nt)
                    #pragma unroll
                    for (int rr = 0; rr < 4; ++rr) {
                        float y = acc0[mt][nt][rr] + bb[nt];
                        y = y > 0.f ? y : 0.f;
                        const int row = mt * 16 + (t >> 4) * 4 + rr;
                        const int col = nt * 16 + (t & 15);
                        tile[row * 64 + (col ^ ((row & 7) << 2))] = y;
                    }
        }

        WAVE_LDS_FENCE();

        // ---- layer 1: 64 -> 64 ----
        f32x4 acc1[2][4] = {};
        #pragma unroll
        for (int kt = 0; kt < 2; ++kt) {
            bf16x8 ah[2], al[2];
            #pragma unroll
            for (int mt = 0; mt < 2; ++mt) {
                float f[8];
                load_frag(tile, mt * 16 + (t & 15), kt * 32 + 8 * (t >> 4), f);
                split8(f, &ah[mt], &al[mt]);
            }
            #pragma unroll
            for (int nt = 0; nt < 4; ++nt) {
                bf16x8 wh = L1h[(kt * 4 + nt) * 64 + t];
                bf16x8 wl = L1l[(kt * 4 + nt) * 64 + t];
                #pragma unroll
                for (int mt = 0; mt < 2; ++mt)
                    acc1[mt][nt] = mfma3(ah[mt], al[mt], wh, wl, acc1[mt][nt]);
            }
        }
        {
            float bb[4];
            #pragma unroll
            for (int nt = 0; nt < 4; ++nt) bb[nt] = bias[64 + nt * 16 + (t & 15)];
            #pragma unroll
            for (int mt = 0; mt < 2; ++mt)
                #pragma unroll
                for (int nt = 0; nt < 4; ++nt)
                    #pragma unroll
                    for (int rr = 0; rr < 4; ++rr) {
                        float y = acc1[mt][nt][rr] + bb[nt];
                        y = y > 0.f ? y : 0.f;
                        const int row = mt * 16 + (t >> 4) * 4 + rr;
                        const int col = nt * 16 + (t & 15);
                        tile[row * 64 + (col ^ ((row & 7) << 2))] = y;
                    }
        }

        WAVE_LDS_FENCE();

        // ---- layer 2: 64 -> 128, fused maxpool + store ----
        bf16x8 a2h[2][2], a2l[2][2];   // [kt][mt]
        #pragma unroll
        for (int kt = 0; kt < 2; ++kt)
            #pragma unroll
            for (int mt = 0; mt < 2; ++mt) {
                float f[8];
                load_frag(tile, mt * 16 + (t & 15), kt * 32 + 8 * (t >> 4), f);
                split8(f, &a2h[kt][mt], &a2l[kt][mt]);
            }

        #pragma unroll
        for (int nh = 0; nh < 2; ++nh) {
            f32x4 acc[2][4] = {};
            #pragma unroll
            for (int kt = 0; kt < 2; ++kt)
                #pragma unroll
                for (int nt = 0; nt < 4; ++nt) {
                    bf16x8 wh = L2h[(kt * 8 + nh * 4 + nt) * 64 + t];
                    bf16x8 wl = L2l[(kt * 8 + nh * 4 + nt) * 64 + t];
                    #pragma unroll
                    for (int mt = 0; mt < 2; ++mt)
                        acc[mt][nt] = mfma3(a2h[kt][mt], a2l[kt][mt], wh, wl, acc[mt][nt]);
                }
            float vnt[4];
            #pragma unroll
            for (int nt = 0; nt < 4; ++nt) {
                float bb = bias[128 + nh * 64 + nt * 16 + (t & 15)];
                float mx = acc[0][nt][0];
                #pragma unroll
                for (int rr = 1; rr < 4; ++rr) mx = fmaxf(mx, acc[0][nt][rr]);
                #pragma unroll
                for (int rr = 0; rr < 4; ++rr) mx = fmaxf(mx, acc[1][nt][rr]);
                float v = mx + bb;
                v = v > 0.f ? v : 0.f;            // relu commutes with max
                v = fmaxf(v, __shfl_xor(v, 16));
                v = fmaxf(v, __shfl_xor(v, 32));
                vnt[nt] = v;
            }
            const int g = t >> 4;
            float v01 = (g & 1) ? vnt[1] : vnt[0];
            float v23 = (g & 1) ? vnt[3] : vnt[2];
            float val = (g & 2) ? v23 : v01;
            size_t o = (size_t)p * 128 + nh * 64 + t;
            out[o] = val;
            out[o + OUT_HALF] = val;
        }
    }
}

extern "C" void kernel_launch(void* const* d_in, const int* in_sizes, int n_in,
                              void* d_out, int out_size, void* d_ws, size_t ws_size,
                              hipStream_t stream) {
    const float* xyz_proj    = (const float*)d_in[0];
    const float* points_proj = (const float*)d_in[1];
    const float* xyz_sampled = (const float*)d_in[2];
    const int*   neighbor_idx= (const int*)  d_in[3];
    const float* valid_mask  = (const float*)d_in[4];
    const float* W0 = (const float*)d_in[5];
    const float* b0 = (const float*)d_in[6];
    const float* g0 = (const float*)d_in[7];
    const float* be0= (const float*)d_in[8];
    const float* W1 = (const float*)d_in[9];
    const float* b1 = (const float*)d_in[10];
    const float* g1 = (const float*)d_in[11];
    const float* be1= (const float*)d_in[12];
    const float* W2 = (const float*)d_in[13];
    const float* b2 = (const float*)d_in[14];
    const float* g2 = (const float*)d_in[15];
    const float* be2= (const float*)d_in[16];

    uint16_t* ws = (uint16_t*)d_ws;

    prep_weights<<<64, 256, 0, stream>>>(W0, b0, g0, be0,
                                         W1, b1, g1, be1,
                                         W2, b2, g2, be2, ws);

    // 32768 points, 2 per wave, 4 waves per block -> 4096 blocks
    pointnet_mfma<<<4096, 256, 0, stream>>>(
        xyz_proj, points_proj, xyz_sampled, neighbor_idx, valid_mask,
        ws, (float*)d_out);
}

// Round 7
// 301.615 us; speedup vs baseline: 1.0519x; 1.0519x over previous
//
#include <hip/hip_runtime.h>
#include <stdint.h>

// Problem constants
#define NN 16384                  // sampled points per batch (h*w)
#define HW 65536                  // H*W
#define OUT_HALF (2 * NN * 128)   // one tuple element, flat floats
#define NP 8                      // points per wave (pipelined)
// MLP: 67 -> 64 -> 64 -> 128 (BN folded), maxpool over K=32 neighbors.
//
// One wave = NP points, pipelined via global_load_lds DMA (zero data VGPRs):
//   loop top: vmcnt(0) [waits gather issued one full compute ago -> free],
//   issue DMA-gather(p_{i+1}) into ping-pong buffer, compute(p_i).
// Round-6 lesson: register-staged prefetch blew VGPR 64->168, occupancy 12%.
// DMA writes LDS linearly (base + lane*16), so the bank-conflict XOR-swizzle
// is applied to the GLOBAL source column (rule #21: pre-swizzled source +
// swizzled reads). Mask multiply moved to layer-0 fragment read (bit-identical:
// still f32 mul before bf16 split).
// Block = 128 thr (2 waves) x 2 tiles x 8KB = 32 KiB -> 5 blocks/CU.
// No __syncthreads (waves independent); intra-wave LDS RAW via
// s_waitcnt lgkmcnt(0) + sched_barrier (rule #18).
//
// Fragment maps (gfx950 16x16x32 bf16, m89-verified):
//   A: row = lane&15, k = 8*(lane>>4)+e ;  B: col = lane&15, same k
//   C/D: col = lane&15, row = 4*(lane>>4)+reg

typedef __attribute__((ext_vector_type(8))) short bf16x8;
typedef __attribute__((ext_vector_type(4))) float f32x4;

// ws layout, uint16 units:
#define WS_L0H 0
#define WS_L0L 6144
#define WS_L1H 12288
#define WS_L1L 16384
#define WS_L2H 20480
#define WS_L2L 28672
#define WS_BIAS 36864

__device__ inline uint16_t f32_to_bf16_rne(float x) {
    uint32_t u = __float_as_uint(x);
    uint32_t r = (u + 0x7FFFu + ((u >> 16) & 1u)) >> 16;
    return (uint16_t)r;
}
__device__ inline float bf16_hi_f32(uint16_t h) {
    return __uint_as_float(((uint32_t)h) << 16);
}
__device__ inline void split2(float v, uint16_t* hi, uint16_t* lo) {
    uint16_t h = f32_to_bf16_rne(v);
    *hi = h;
    *lo = f32_to_bf16_rne(v - bf16_hi_f32(h));
}

// ---------------- weight prep (runs once per launch, tiny) ----------------
__global__ void prep_weights(
    const float* __restrict__ W0, const float* __restrict__ b0,
    const float* __restrict__ g0, const float* __restrict__ be0,
    const float* __restrict__ W1, const float* __restrict__ b1,
    const float* __restrict__ g1, const float* __restrict__ be1,
    const float* __restrict__ W2, const float* __restrict__ b2,
    const float* __restrict__ g2, const float* __restrict__ be2,
    uint16_t* __restrict__ ws)
{
    const int tid = blockIdx.x * blockDim.x + threadIdx.x;
    const int nth = gridDim.x * blockDim.x;

    // L0: [3 kt][4 nt][64 lane][8 e]; k 0..63 -> W0 row 3+k, 64..66 -> row k-64
    for (int i = tid; i < 6144; i += nth) {
        int e = i & 7, lane = (i >> 3) & 63, nt = (i >> 9) & 3, kt = i >> 11;
        int k = kt * 32 + 8 * (lane >> 4) + e;
        int n = nt * 16 + (lane & 15);
        float v = 0.f;
        if (k < 64)       v = W0[(3 + k) * 64 + n] * g0[n];
        else if (k < 67)  v = W0[(k - 64) * 64 + n] * g0[n];
        uint16_t hi, lo; split2(v, &hi, &lo);
        ws[WS_L0H + i] = hi; ws[WS_L0L + i] = lo;
    }
    for (int i = tid; i < 4096; i += nth) {
        int e = i & 7, lane = (i >> 3) & 63, nt = (i >> 9) & 3, kt = i >> 11;
        int k = kt * 32 + 8 * (lane >> 4) + e;
        int n = nt * 16 + (lane & 15);
        float v = W1[k * 64 + n] * g1[n];
        uint16_t hi, lo; split2(v, &hi, &lo);
        ws[WS_L1H + i] = hi; ws[WS_L1L + i] = lo;
    }
    for (int i = tid; i < 8192; i += nth) {
        int e = i & 7, lane = (i >> 3) & 63, nt = (i >> 9) & 7, kt = i >> 12;
        int k = kt * 32 + 8 * (lane >> 4) + e;
        int n = nt * 16 + (lane & 15);
        float v = W2[k * 128 + n] * g2[n];
        uint16_t hi, lo; split2(v, &hi, &lo);
        ws[WS_L2H + i] = hi; ws[WS_L2L + i] = lo;
    }
    float* bias = (float*)(ws + WS_BIAS);
    for (int i = tid; i < 64; i += nth)  bias[i]       = b0[i] * g0[i] + be0[i];
    for (int i = tid; i < 64; i += nth)  bias[64 + i]  = b1[i] * g1[i] + be1[i];
    for (int i = tid; i < 128; i += nth) bias[128 + i] = b2[i] * g2[i] + be2[i];
}

// ---------------- main kernel helpers ----------------
__device__ inline uint32_t cvt_pk_bf16(float a, float b) {
    uint32_t r;
    asm("v_cvt_pk_bf16_f32 %0, %1, %2" : "=v"(r) : "v"(a), "v"(b));
    return r;
}

union frag_u { uint32_t w[4]; bf16x8 v; };

// split 8 f32 -> hi/lo bf16x8 via packed converts (lo = a - f32(hi), exact)
__device__ inline void split8(const float* f, bf16x8* hi, bf16x8* lo) {
    frag_u H, L;
    #pragma unroll
    for (int p2 = 0; p2 < 4; ++p2) {
        float a = f[2 * p2], b = f[2 * p2 + 1];
        uint32_t h = cvt_pk_bf16(a, b);
        float ha = __uint_as_float(h << 16);
        float hb = __uint_as_float(h & 0xffff0000u);
        uint32_t l = cvt_pk_bf16(a - ha, b - hb);
        H.w[p2] = h; L.w[p2] = l;
    }
    *hi = H.v; *lo = L.v;
}

__device__ inline f32x4 mfma3(bf16x8 ah, bf16x8 al, bf16x8 wh, bf16x8 wl, f32x4 c) {
    c = __builtin_amdgcn_mfma_f32_16x16x32_bf16(ah, wh, c, 0, 0, 0);
    c = __builtin_amdgcn_mfma_f32_16x16x32_bf16(al, wh, c, 0, 0, 0);
    c = __builtin_amdgcn_mfma_f32_16x16x32_bf16(ah, wl, c, 0, 0, 0);
    return c;
}

// swizzled f32 tile [32][64]: elem = row*64 + (col ^ ((row&7)<<2))
__device__ inline void load_frag(const float* tile, int row, int c0, float* f) {
    const int sw = (row & 7) << 2;
    *(float4*)&f[0] = *(const float4*)&tile[row * 64 + (c0 ^ sw)];
    *(float4*)&f[4] = *(const float4*)&tile[row * 64 + ((c0 + 4) ^ sw)];
}

#define WAVE_LDS_FENCE() do { \
    asm volatile("s_waitcnt lgkmcnt(0)" ::: "memory"); \
    __builtin_amdgcn_sched_barrier(0); \
} while (0)

// DMA one 16B chunk per lane into LDS (dest = ldsbase + lane*16)
__device__ inline void gload16_lds(const float* g, float* lds) {
    __builtin_amdgcn_global_load_lds(
        (const __attribute__((address_space(1))) void*)g,
        (__attribute__((address_space(3))) void*)lds,
        16, 0, 0);
}

// Issue the full 32x64 f32 gather for one point via 8 DMA ops.
// Instruction q covers LDS floats [256q, 256q+256) = rows 4q..4q+3 (linear);
// lane L -> row 4q+(L>>4), phys col 4*(L&15). Source col is pre-swizzled so
// LDS holds value(row, col) at phys col = col ^ ((row&7)<<2).
__device__ inline void gather_issue(float* tile, int rowbase, int idxv,
                                    const float* pts, int t) {
    #pragma unroll
    for (int q = 0; q < 8; ++q) {
        const int row  = 4 * q + (t >> 4);
        const int scol = (4 * (t & 15)) ^ ((row & 7) << 2);
        const int ridx = __shfl(idxv, row);              // idx lives in lanes 0..31
        const float* g = pts + (size_t)(rowbase + ridx) * 64 + scol;
        gload16_lds(g, tile + q * 256);
    }
}

__device__ inline void stage_load(int p, int r,
                                  const int* __restrict__ nidx,
                                  const float* __restrict__ vmask,
                                  const float* __restrict__ xyz_proj,
                                  const float* __restrict__ xyz_sampled,
                                  int* idx, float* m,
                                  float* xd0, float* xd1, float* xd2, int* rb) {
    *rb  = (p >> 14) << 16;                  // b * HW
    *idx = nidx[(size_t)p * 32 + r];
    *m   = vmask[(size_t)p * 32 + r];
    const float* xs = xyz_proj + (size_t)(*rb + *idx) * 3;
    *xd0 = xs[0] * (*m) - xyz_sampled[(size_t)p * 3 + 0];
    *xd1 = xs[1] * (*m) - xyz_sampled[(size_t)p * 3 + 1];
    *xd2 = xs[2] * (*m) - xyz_sampled[(size_t)p * 3 + 2];
}

__global__ __launch_bounds__(128)
void pointnet_mfma(
    const float* __restrict__ xyz_proj,      // [B, H*W, 3]
    const float* __restrict__ points_proj,   // [B, H*W, 64]
    const float* __restrict__ xyz_sampled,   // [B, N, 3]
    const int*   __restrict__ nidx,          // [B, N, 32]
    const float* __restrict__ vmask,         // [B, N, 32, 1]
    const uint16_t* __restrict__ wf,
    float* __restrict__ out)
{
    __shared__ float s_lds[2][2][2048];      // 2 waves x 2 tiles x 8KB = 32 KiB

    // XCD-aware bijective swizzle (grid 2048, 8 XCDs, 256 blocks per XCD)
    const int bid = blockIdx.x;
    const int swz = (bid & 7) * 256 + (bid >> 3);

    const int t     = threadIdx.x & 63;
    const int widx  = threadIdx.x >> 6;
    const int wid   = swz * 2 + widx;        // wave id in [0, 4096)
    const int pbase = wid * NP;              // NP consecutive points (no batch cross)

    float* buf0 = s_lds[widx][0];
    float* buf1 = s_lds[widx][1];

    const bf16x8* L0h = (const bf16x8*)(wf + WS_L0H);
    const bf16x8* L0l = (const bf16x8*)(wf + WS_L0L);
    const bf16x8* L1h = (const bf16x8*)(wf + WS_L1H);
    const bf16x8* L1l = (const bf16x8*)(wf + WS_L1L);
    const bf16x8* L2h = (const bf16x8*)(wf + WS_L2H);
    const bf16x8* L2l = (const bf16x8*)(wf + WS_L2L);
    const float*  bias = (const float*)(wf + WS_BIAS);

    const int r = t & 31;

    // ---- prologue: stage A (point 0) + issue its gather; stage B (point 1) ----
    int idxA, rbA; float mA, xdA0, xdA1, xdA2;
    stage_load(pbase, r, nidx, vmask, xyz_proj, xyz_sampled,
               &idxA, &mA, &xdA0, &xdA1, &xdA2, &rbA);
    gather_issue(buf0, rbA, idxA, points_proj, t);

    int idxB = 0, rbB = 0; float mB = 0.f, xdB0 = 0.f, xdB1 = 0.f, xdB2 = 0.f;
    stage_load(pbase + 1, r, nidx, vmask, xyz_proj, xyz_sampled,
               &idxB, &mB, &xdB0, &xdB1, &xdB2, &rbB);

    #pragma unroll 1
    for (int i = 0; i < NP; ++i) {
        float* cur = (i & 1) ? buf1 : buf0;
        float* nxt = (i & 1) ? buf0 : buf1;

        // wait for cur's DMA (issued one full compute ago) + drain stores
        asm volatile("s_waitcnt vmcnt(0)" ::: "memory");
        __builtin_amdgcn_sched_barrier(0);

        // issue next point's gather; hides under this point's compute
        if (i + 1 < NP) gather_issue(nxt, rbB, idxB, points_proj, t);

        // start stage C loads (point i+2); lands during compute
        int idxC = 0, rbC = 0; float mC = 0.f, xdC0 = 0.f, xdC1 = 0.f, xdC2 = 0.f;
        if (i + 2 < NP)
            stage_load(pbase + i + 2, r, nidx, vmask, xyz_proj, xyz_sampled,
                       &idxC, &mC, &xdC0, &xdC1, &xdC2, &rbC);

        // per-row mask factors for layer-0 fragment reads
        const float mr0 = __shfl(mA, t & 15);
        const float mr1 = __shfl(mA, 16 + (t & 15));

        // ---- layer 0: K = 64 (pts) + 3 (xyz) -> 64 ----
        f32x4 acc0[2][4] = {};
        #pragma unroll
        for (int kt = 0; kt < 2; ++kt) {
            bf16x8 ah[2], al[2];
            #pragma unroll
            for (int mt = 0; mt < 2; ++mt) {
                float f[8];
                load_frag(cur, mt * 16 + (t & 15), kt * 32 + 8 * (t >> 4), f);
                const float mm = mt ? mr1 : mr0;
                #pragma unroll
                for (int e = 0; e < 8; ++e) f[e] *= mm;
                split8(f, &ah[mt], &al[mt]);
            }
            #pragma unroll
            for (int nt = 0; nt < 4; ++nt) {
                bf16x8 wh = L0h[(kt * 4 + nt) * 64 + t];
                bf16x8 wl = L0l[(kt * 4 + nt) * 64 + t];
                #pragma unroll
                for (int mt = 0; mt < 2; ++mt)
                    acc0[mt][nt] = mfma3(ah[mt], al[mt], wh, wl, acc0[mt][nt]);
            }
        }
        {   // xyz k-step (kt=2): lanes g==0 carry e=0..2; rest zero
            const int srow = t & 15;
            float a0 = __shfl(xdA0, srow),      a1 = __shfl(xdA1, srow),      a2 = __shfl(xdA2, srow);
            float c0 = __shfl(xdA0, srow + 16), c1 = __shfl(xdA1, srow + 16), c2 = __shfl(xdA2, srow + 16);
            const bool g0 = (t >> 4) == 0;
            float f0[8] = { g0 ? a0 : 0.f, g0 ? a1 : 0.f, g0 ? a2 : 0.f, 0.f, 0.f, 0.f, 0.f, 0.f };
            float f1[8] = { g0 ? c0 : 0.f, g0 ? c1 : 0.f, g0 ? c2 : 0.f, 0.f, 0.f, 0.f, 0.f, 0.f };
            bf16x8 ah[2], al[2];
            split8(f0, &ah[0], &al[0]);
            split8(f1, &ah[1], &al[1]);
            #pragma unroll
            for (int nt = 0; nt < 4; ++nt) {
                bf16x8 wh = L0h[(8 + nt) * 64 + t];
                bf16x8 wl = L0l[(8 + nt) * 64 + t];
                #pragma unroll
                for (int mt = 0; mt < 2; ++mt)
                    acc0[mt][nt] = mfma3(ah[mt], al[mt], wh, wl, acc0[mt][nt]);
            }
        }
        {   // bias + relu -> writeback (swizzled); input fully consumed above
            float bb[4];
            #pragma unroll
            for (int nt = 0; nt < 4; ++nt) bb[nt] = bias[nt * 16 + (t & 15)];
            #pragma unroll
            for (int mt = 0; mt < 2; ++mt)
                #pragma unroll
                for (int nt = 0; nt < 4; ++nt)
                    #pragma unroll
                    for (int rr = 0; rr < 4; ++rr) {
                        float y = acc0[mt][nt][rr] + bb[nt];
                        y = y > 0.f ? y : 0.f;
                        const int row = mt * 16 + (t >> 4) * 4 + rr;
                        const int col = nt * 16 + (t & 15);
                        cur[row * 64 + (col ^ ((row & 7) << 2))] = y;
                    }
        }

        WAVE_LDS_FENCE();

        // ---- layer 1: 64 -> 64 ----
        f32x4 acc1[2][4] = {};
        #pragma unroll
        for (int kt = 0; kt < 2; ++kt) {
            bf16x8 ah[2], al[2];
            #pragma unroll
            for (int mt = 0; mt < 2; ++mt) {
                float f[8];
                load_frag(cur, mt * 16 + (t & 15), kt * 32 + 8 * (t >> 4), f);
                split8(f, &ah[mt], &al[mt]);
            }
            #pragma unroll
            for (int nt = 0; nt < 4; ++nt) {
                bf16x8 wh = L1h[(kt * 4 + nt) * 64 + t];
                bf16x8 wl = L1l[(kt * 4 + nt) * 64 + t];
                #pragma unroll
                for (int mt = 0; mt < 2; ++mt)
                    acc1[mt][nt] = mfma3(ah[mt], al[mt], wh, wl, acc1[mt][nt]);
            }
        }
        {
            float bb[4];
            #pragma unroll
            for (int nt = 0; nt < 4; ++nt) bb[nt] = bias[64 + nt * 16 + (t & 15)];
            #pragma unroll
            for (int mt = 0; mt < 2; ++mt)
                #pragma unroll
                for (int nt = 0; nt < 4; ++nt)
                    #pragma unroll
                    for (int rr = 0; rr < 4; ++rr) {
                        float y = acc1[mt][nt][rr] + bb[nt];
                        y = y > 0.f ? y : 0.f;
                        const int row = mt * 16 + (t >> 4) * 4 + rr;
                        const int col = nt * 16 + (t & 15);
                        cur[row * 64 + (col ^ ((row & 7) << 2))] = y;
                    }
        }

        WAVE_LDS_FENCE();

        // ---- layer 2: 64 -> 128, fused maxpool + store ----
        bf16x8 a2h[2][2], a2l[2][2];   // [kt][mt]
        #pragma unroll
        for (int kt = 0; kt < 2; ++kt)
            #pragma unroll
            for (int mt = 0; mt < 2; ++mt) {
                float f[8];
                load_frag(cur, mt * 16 + (t & 15), kt * 32 + 8 * (t >> 4), f);
                split8(f, &a2h[kt][mt], &a2l[kt][mt]);
            }

        const int p = pbase + i;
        #pragma unroll
        for (int nh = 0; nh < 2; ++nh) {
            f32x4 acc[2][4] = {};
            #pragma unroll
            for (int kt = 0; kt < 2; ++kt)
                #pragma unroll
                for (int nt = 0; nt < 4; ++nt) {
                    bf16x8 wh = L2h[(kt * 8 + nh * 4 + nt) * 64 + t];
                    bf16x8 wl = L2l[(kt * 8 + nh * 4 + nt) * 64 + t];
                    #pragma unroll
                    for (int mt = 0; mt < 2; ++mt)
                        acc[mt][nt] = mfma3(a2h[kt][mt], a2l[kt][mt], wh, wl, acc[mt][nt]);
                }
            float vnt[4];
            #pragma unroll
            for (int nt = 0; nt < 4; ++nt) {
                float bb = bias[128 + nh * 64 + nt * 16 + (t & 15)];
                float mx = acc[0][nt][0];
                #pragma unroll
                for (int rr = 1; rr < 4; ++rr) mx = fmaxf(mx, acc[0][nt][rr]);
                #pragma unroll
                for (int rr = 0; rr < 4; ++rr) mx = fmaxf(mx, acc[1][nt][rr]);
                float v = mx + bb;
                v = v > 0.f ? v : 0.f;            // relu commutes with max
                v = fmaxf(v, __shfl_xor(v, 16));
                v = fmaxf(v, __shfl_xor(v, 32));
                vnt[nt] = v;
            }
            const int g = t >> 4;
            float v01 = (g & 1) ? vnt[1] : vnt[0];
            float v23 = (g & 1) ? vnt[3] : vnt[2];
            float val = (g & 2) ? v23 : v01;
            size_t o = (size_t)p * 128 + nh * 64 + t;
            out[o] = val;
            out[o + OUT_HALF] = val;
        }

        // rotate pipeline stages
        mA = mB; xdA0 = xdB0; xdA1 = xdB1; xdA2 = xdB2;
        idxB = idxC; mB = mC; xdB0 = xdC0; xdB1 = xdC1; xdB2 = xdC2; rbB = rbC;
    }
}

extern "C" void kernel_launch(void* const* d_in, const int* in_sizes, int n_in,
                              void* d_out, int out_size, void* d_ws, size_t ws_size,
                              hipStream_t stream) {
    const float* xyz_proj    = (const float*)d_in[0];
    const float* points_proj = (const float*)d_in[1];
    const float* xyz_sampled = (const float*)d_in[2];
    const int*   neighbor_idx= (const int*)  d_in[3];
    const float* valid_mask  = (const float*)d_in[4];
    const float* W0 = (const float*)d_in[5];
    const float* b0 = (const float*)d_in[6];
    const float* g0 = (const float*)d_in[7];
    const float* be0= (const float*)d_in[8];
    const float* W1 = (const float*)d_in[9];
    const float* b1 = (const float*)d_in[10];
    const float* g1 = (const float*)d_in[11];
    const float* be1= (const float*)d_in[12];
    const float* W2 = (const float*)d_in[13];
    const float* b2 = (const float*)d_in[14];
    const float* g2 = (const float*)d_in[15];
    const float* be2= (const float*)d_in[16];

    uint16_t* ws = (uint16_t*)d_ws;

    prep_weights<<<64, 256, 0, stream>>>(W0, b0, g0, be0,
                                         W1, b1, g1, be1,
                                         W2, b2, g2, be2, ws);

    // 32768 points, 8 per wave, 2 waves per block -> 2048 blocks
    pointnet_mfma<<<2048, 128, 0, stream>>>(
        xyz_proj, points_proj, xyz_sampled, neighbor_idx, valid_mask,
        ws, (float*)d_out);
}

// Round 8
// 145.097 us; speedup vs baseline: 2.1866x; 2.0787x over previous
//
#include <hip/hip_runtime.h>
#include <stdint.h>

// Problem constants
#define NN 16384                  // sampled points per batch (h*w)
#define HW 65536                  // H*W
#define OUT_HALF (2 * NN * 128)   // one tuple element, flat floats
// MLP: 67 -> 64 -> 64 -> 128 (BN folded), maxpool over K=32 neighbors.
//
// One wave = one point (round-5 structure; rounds 6/7 showed per-wave
// pipelining explodes VGPR 64->168 and collapses occupancy 43%->12%).
// Round-8 changes, both VGPR-bounded:
//  (1) L0 A-fragments loaded DIRECTLY from global (lane reads 32 contiguous
//      bytes of its gathered row; idx/mask via __shfl) -- no gather LDS
//      round-trip, one fewer fence. LDS tile now only carries act0/act1.
//  (2) Weight fragments batch-loaded into statically-indexed arrays per
//      kt-step BEFORE the MFMA chain (explicit load-to-use distance; at
//      VGPR=64 the compiler was issuing each 16B load right before use).
// fp32 accuracy via hi/lo bf16 split, 3 passes: ah*wh + al*wh + ah*wl.
// No __syncthreads (waves independent); intra-wave LDS RAW ordering via
// s_waitcnt lgkmcnt(0) + sched_barrier (rule #18).
// LDS = 4 waves x [32][64] f32 XOR-swizzled = 32 KiB -> 5 blocks/CU.
// XCD swizzle (T1): grid 8192 %8==0, contiguous 1024-block chunk per XCD.
//
// Fragment maps (gfx950 16x16x32 bf16, m89-verified):
//   A: row = lane&15, k = 8*(lane>>4)+e ;  B: col = lane&15, same k
//   C/D: col = lane&15, row = 4*(lane>>4)+reg

typedef __attribute__((ext_vector_type(8))) short bf16x8;
typedef __attribute__((ext_vector_type(4))) float f32x4;

// ws layout, uint16 units:
#define WS_L0H 0
#define WS_L0L 6144
#define WS_L1H 12288
#define WS_L1L 16384
#define WS_L2H 20480
#define WS_L2L 28672
#define WS_BIAS 36864

__device__ inline uint16_t f32_to_bf16_rne(float x) {
    uint32_t u = __float_as_uint(x);
    uint32_t r = (u + 0x7FFFu + ((u >> 16) & 1u)) >> 16;
    return (uint16_t)r;
}
__device__ inline float bf16_hi_f32(uint16_t h) {
    return __uint_as_float(((uint32_t)h) << 16);
}
__device__ inline void split2(float v, uint16_t* hi, uint16_t* lo) {
    uint16_t h = f32_to_bf16_rne(v);
    *hi = h;
    *lo = f32_to_bf16_rne(v - bf16_hi_f32(h));
}

// ---------------- weight prep (runs once per launch, tiny) ----------------
__global__ void prep_weights(
    const float* __restrict__ W0, const float* __restrict__ b0,
    const float* __restrict__ g0, const float* __restrict__ be0,
    const float* __restrict__ W1, const float* __restrict__ b1,
    const float* __restrict__ g1, const float* __restrict__ be1,
    const float* __restrict__ W2, const float* __restrict__ b2,
    const float* __restrict__ g2, const float* __restrict__ be2,
    uint16_t* __restrict__ ws)
{
    const int tid = blockIdx.x * blockDim.x + threadIdx.x;
    const int nth = gridDim.x * blockDim.x;

    // L0: [3 kt][4 nt][64 lane][8 e]; k 0..63 -> W0 row 3+k, 64..66 -> row k-64
    for (int i = tid; i < 6144; i += nth) {
        int e = i & 7, lane = (i >> 3) & 63, nt = (i >> 9) & 3, kt = i >> 11;
        int k = kt * 32 + 8 * (lane >> 4) + e;
        int n = nt * 16 + (lane & 15);
        float v = 0.f;
        if (k < 64)       v = W0[(3 + k) * 64 + n] * g0[n];
        else if (k < 67)  v = W0[(k - 64) * 64 + n] * g0[n];
        uint16_t hi, lo; split2(v, &hi, &lo);
        ws[WS_L0H + i] = hi; ws[WS_L0L + i] = lo;
    }
    for (int i = tid; i < 4096; i += nth) {
        int e = i & 7, lane = (i >> 3) & 63, nt = (i >> 9) & 3, kt = i >> 11;
        int k = kt * 32 + 8 * (lane >> 4) + e;
        int n = nt * 16 + (lane & 15);
        float v = W1[k * 64 + n] * g1[n];
        uint16_t hi, lo; split2(v, &hi, &lo);
        ws[WS_L1H + i] = hi; ws[WS_L1L + i] = lo;
    }
    for (int i = tid; i < 8192; i += nth) {
        int e = i & 7, lane = (i >> 3) & 63, nt = (i >> 9) & 7, kt = i >> 12;
        int k = kt * 32 + 8 * (lane >> 4) + e;
        int n = nt * 16 + (lane & 15);
        float v = W2[k * 128 + n] * g2[n];
        uint16_t hi, lo; split2(v, &hi, &lo);
        ws[WS_L2H + i] = hi; ws[WS_L2L + i] = lo;
    }
    float* bias = (float*)(ws + WS_BIAS);
    for (int i = tid; i < 64; i += nth)  bias[i]       = b0[i] * g0[i] + be0[i];
    for (int i = tid; i < 64; i += nth)  bias[64 + i]  = b1[i] * g1[i] + be1[i];
    for (int i = tid; i < 128; i += nth) bias[128 + i] = b2[i] * g2[i] + be2[i];
}

// ---------------- main kernel helpers ----------------
__device__ inline uint32_t cvt_pk_bf16(float a, float b) {
    uint32_t r;
    asm("v_cvt_pk_bf16_f32 %0, %1, %2" : "=v"(r) : "v"(a), "v"(b));
    return r;
}

union frag_u { uint32_t w[4]; bf16x8 v; };

// split 8 f32 -> hi/lo bf16x8 via packed converts (lo = a - f32(hi), exact)
__device__ inline void split8(const float* f, bf16x8* hi, bf16x8* lo) {
    frag_u H, L;
    #pragma unroll
    for (int p2 = 0; p2 < 4; ++p2) {
        float a = f[2 * p2], b = f[2 * p2 + 1];
        uint32_t h = cvt_pk_bf16(a, b);
        float ha = __uint_as_float(h << 16);
        float hb = __uint_as_float(h & 0xffff0000u);
        uint32_t l = cvt_pk_bf16(a - ha, b - hb);
        H.w[p2] = h; L.w[p2] = l;
    }
    *hi = H.v; *lo = L.v;
}

__device__ inline f32x4 mfma3(bf16x8 ah, bf16x8 al, bf16x8 wh, bf16x8 wl, f32x4 c) {
    c = __builtin_amdgcn_mfma_f32_16x16x32_bf16(ah, wh, c, 0, 0, 0);
    c = __builtin_amdgcn_mfma_f32_16x16x32_bf16(al, wh, c, 0, 0, 0);
    c = __builtin_amdgcn_mfma_f32_16x16x32_bf16(ah, wl, c, 0, 0, 0);
    return c;
}

// swizzled f32 tile [32][64]: elem = row*64 + (col ^ ((row&7)<<2))
__device__ inline void load_frag(const float* tile, int row, int c0, float* f) {
    const int sw = (row & 7) << 2;
    *(float4*)&f[0] = *(const float4*)&tile[row * 64 + (c0 ^ sw)];
    *(float4*)&f[4] = *(const float4*)&tile[row * 64 + ((c0 + 4) ^ sw)];
}

#define WAVE_LDS_FENCE() do { \
    asm volatile("s_waitcnt lgkmcnt(0)" ::: "memory"); \
    __builtin_amdgcn_sched_barrier(0); \
} while (0)

__global__ __launch_bounds__(256)
void pointnet_mfma(
    const float* __restrict__ xyz_proj,      // [B, H*W, 3]
    const float* __restrict__ points_proj,   // [B, H*W, 64]
    const float* __restrict__ xyz_sampled,   // [B, N, 3]
    const int*   __restrict__ nidx,          // [B, N, 32]
    const float* __restrict__ vmask,         // [B, N, 32, 1]
    const uint16_t* __restrict__ wf,
    float* __restrict__ out)
{
    __shared__ float s_feat[4][2048];   // 4 waves x 8 KiB act tile = 32 KiB

    // XCD-aware bijective swizzle (grid 8192, 8 XCDs, 1024 blocks per XCD)
    const int bid = blockIdx.x;
    const int swz = (bid & 7) * 1024 + (bid >> 3);

    const int t    = threadIdx.x & 63;
    const int widx = threadIdx.x >> 6;
    const int p    = swz * 4 + widx;          // point id in [0, 2*NN)
    const int rb   = (p >> 14) << 16;          // b * HW

    float* tile = s_feat[widx];

    const bf16x8* L0h = (const bf16x8*)(wf + WS_L0H);
    const bf16x8* L0l = (const bf16x8*)(wf + WS_L0L);
    const bf16x8* L1h = (const bf16x8*)(wf + WS_L1H);
    const bf16x8* L1l = (const bf16x8*)(wf + WS_L1L);
    const bf16x8* L2h = (const bf16x8*)(wf + WS_L2H);
    const bf16x8* L2l = (const bf16x8*)(wf + WS_L2L);
    const float*  bias = (const float*)(wf + WS_BIAS);

    const int r = t & 31;

    // ---- per-neighbor scalars (lanes 0..31 authoritative) ----
    const int   idx = nidx[(size_t)p * 32 + r];
    const float m   = vmask[(size_t)p * 32 + r];
    float xd0, xd1, xd2;
    {
        const float* xs = xyz_proj + (size_t)(rb + idx) * 3;
        xd0 = xs[0] * m - xyz_sampled[(size_t)p * 3 + 0];
        xd1 = xs[1] * m - xyz_sampled[(size_t)p * 3 + 1];
        xd2 = xs[2] * m - xyz_sampled[(size_t)p * 3 + 2];
    }

    // ---- L0 A-fragment rows: direct global gather (no LDS round-trip) ----
    const int  fr0 = t & 15;                  // m-tile 0 row
    const int  fr1 = 16 + (t & 15);           // m-tile 1 row
    const int  gi0 = __shfl(idx, fr0);
    const int  gi1 = __shfl(idx, fr1);
    const float mm0 = __shfl(m, fr0);
    const float mm1 = __shfl(m, fr1);
    const float* row0 = points_proj + (size_t)(rb + gi0) * 64 + 8 * (t >> 4);
    const float* row1 = points_proj + (size_t)(rb + gi1) * 64 + 8 * (t >> 4);

    float fr[2][2][8];   // [kt][mt][e] -- all loads issued up front
    #pragma unroll
    for (int kt = 0; kt < 2; ++kt) {
        *(float4*)&fr[kt][0][0] = ((const float4*)(row0 + kt * 32))[0];
        *(float4*)&fr[kt][0][4] = ((const float4*)(row0 + kt * 32))[1];
        *(float4*)&fr[kt][1][0] = ((const float4*)(row1 + kt * 32))[0];
        *(float4*)&fr[kt][1][4] = ((const float4*)(row1 + kt * 32))[1];
    }

    // ---- layer 0: K = 64 (pts) + 3 (xyz) -> 64 ----
    f32x4 acc0[2][4] = {};
    #pragma unroll
    for (int kt = 0; kt < 2; ++kt) {
        // batch all 8 weight fragments for this kt (static indices -> regs)
        bf16x8 wh[4], wl[4];
        #pragma unroll
        for (int nt = 0; nt < 4; ++nt) {
            wh[nt] = L0h[(kt * 4 + nt) * 64 + t];
            wl[nt] = L0l[(kt * 4 + nt) * 64 + t];
        }
        bf16x8 ah[2], al[2];
        #pragma unroll
        for (int mt = 0; mt < 2; ++mt) {
            const float mm = mt ? mm1 : mm0;
            float f[8];
            #pragma unroll
            for (int e = 0; e < 8; ++e) f[e] = fr[kt][mt][e] * mm;
            split8(f, &ah[mt], &al[mt]);
        }
        #pragma unroll
        for (int nt = 0; nt < 4; ++nt)
            #pragma unroll
            for (int mt = 0; mt < 2; ++mt)
                acc0[mt][nt] = mfma3(ah[mt], al[mt], wh[nt], wl[nt], acc0[mt][nt]);
    }
    {   // xyz k-step (kt=2): lanes g==0 carry e=0..2; rest zero
        bf16x8 wh[4], wl[4];
        #pragma unroll
        for (int nt = 0; nt < 4; ++nt) {
            wh[nt] = L0h[(8 + nt) * 64 + t];
            wl[nt] = L0l[(8 + nt) * 64 + t];
        }
        const int srow = t & 15;
        float a0 = __shfl(xd0, srow),      a1 = __shfl(xd1, srow),      a2 = __shfl(xd2, srow);
        float c0 = __shfl(xd0, srow + 16), c1 = __shfl(xd1, srow + 16), c2 = __shfl(xd2, srow + 16);
        const bool g0 = (t >> 4) == 0;
        float f0[8] = { g0 ? a0 : 0.f, g0 ? a1 : 0.f, g0 ? a2 : 0.f, 0.f, 0.f, 0.f, 0.f, 0.f };
        float f1[8] = { g0 ? c0 : 0.f, g0 ? c1 : 0.f, g0 ? c2 : 0.f, 0.f, 0.f, 0.f, 0.f, 0.f };
        bf16x8 ah[2], al[2];
        split8(f0, &ah[0], &al[0]);
        split8(f1, &ah[1], &al[1]);
        #pragma unroll
        for (int nt = 0; nt < 4; ++nt)
            #pragma unroll
            for (int mt = 0; mt < 2; ++mt)
                acc0[mt][nt] = mfma3(ah[mt], al[mt], wh[nt], wl[nt], acc0[mt][nt]);
    }
    {   // bias + relu -> act0 into swizzled LDS tile
        float bb[4];
        #pragma unroll
        for (int nt = 0; nt < 4; ++nt) bb[nt] = bias[nt * 16 + (t & 15)];
        #pragma unroll
        for (int mt = 0; mt < 2; ++mt)
            #pragma unroll
            for (int nt = 0; nt < 4; ++nt)
                #pragma unroll
                for (int rr = 0; rr < 4; ++rr) {
                    float y = acc0[mt][nt][rr] + bb[nt];
                    y = y > 0.f ? y : 0.f;
                    const int row = mt * 16 + (t >> 4) * 4 + rr;
                    const int col = nt * 16 + (t & 15);
                    tile[row * 64 + (col ^ ((row & 7) << 2))] = y;
                }
    }

    WAVE_LDS_FENCE();

    // ---- layer 1: 64 -> 64 ----
    f32x4 acc1[2][4] = {};
    #pragma unroll
    for (int kt = 0; kt < 2; ++kt) {
        bf16x8 wh[4], wl[4];
        #pragma unroll
        for (int nt = 0; nt < 4; ++nt) {
            wh[nt] = L1h[(kt * 4 + nt) * 64 + t];
            wl[nt] = L1l[(kt * 4 + nt) * 64 + t];
        }
        bf16x8 ah[2], al[2];
        #pragma unroll
        for (int mt = 0; mt < 2; ++mt) {
            float f[8];
            load_frag(tile, mt * 16 + (t & 15), kt * 32 + 8 * (t >> 4), f);
            split8(f, &ah[mt], &al[mt]);
        }
        #pragma unroll
        for (int nt = 0; nt < 4; ++nt)
            #pragma unroll
            for (int mt = 0; mt < 2; ++mt)
                acc1[mt][nt] = mfma3(ah[mt], al[mt], wh[nt], wl[nt], acc1[mt][nt]);
    }
    {
        float bb[4];
        #pragma unroll
        for (int nt = 0; nt < 4; ++nt) bb[nt] = bias[64 + nt * 16 + (t & 15)];
        #pragma unroll
        for (int mt = 0; mt < 2; ++mt)
            #pragma unroll
            for (int nt = 0; nt < 4; ++nt)
                #pragma unroll
                for (int rr = 0; rr < 4; ++rr) {
                    float y = acc1[mt][nt][rr] + bb[nt];
                    y = y > 0.f ? y : 0.f;
                    const int row = mt * 16 + (t >> 4) * 4 + rr;
                    const int col = nt * 16 + (t & 15);
                    tile[row * 64 + (col ^ ((row & 7) << 2))] = y;
                }
    }

    WAVE_LDS_FENCE();

    // ---- layer 2: 64 -> 128, fused maxpool + store ----
    bf16x8 a2h[2][2], a2l[2][2];   // [kt][mt]
    #pragma unroll
    for (int kt = 0; kt < 2; ++kt)
        #pragma unroll
        for (int mt = 0; mt < 2; ++mt) {
            float f[8];
            load_frag(tile, mt * 16 + (t & 15), kt * 32 + 8 * (t >> 4), f);
            split8(f, &a2h[kt][mt], &a2l[kt][mt]);
        }

    #pragma unroll
    for (int nh = 0; nh < 2; ++nh) {
        f32x4 acc[2][4] = {};
        #pragma unroll
        for (int kt = 0; kt < 2; ++kt) {
            bf16x8 wh[4], wl[4];
            #pragma unroll
            for (int nt = 0; nt < 4; ++nt) {
                wh[nt] = L2h[(kt * 8 + nh * 4 + nt) * 64 + t];
                wl[nt] = L2l[(kt * 8 + nh * 4 + nt) * 64 + t];
            }
            #pragma unroll
            for (int nt = 0; nt < 4; ++nt)
                #pragma unroll
                for (int mt = 0; mt < 2; ++mt)
                    acc[mt][nt] = mfma3(a2h[kt][mt], a2l[kt][mt], wh[nt], wl[nt], acc[mt][nt]);
        }
        float vnt[4];
        #pragma unroll
        for (int nt = 0; nt < 4; ++nt) {
            float bb = bias[128 + nh * 64 + nt * 16 + (t & 15)];
            float mx = acc[0][nt][0];
            #pragma unroll
            for (int rr = 1; rr < 4; ++rr) mx = fmaxf(mx, acc[0][nt][rr]);
            #pragma unroll
            for (int rr = 0; rr < 4; ++rr) mx = fmaxf(mx, acc[1][nt][rr]);
            float v = mx + bb;
            v = v > 0.f ? v : 0.f;            // relu commutes with max
            v = fmaxf(v, __shfl_xor(v, 16));
            v = fmaxf(v, __shfl_xor(v, 32));
            vnt[nt] = v;
        }
        const int g = t >> 4;
        float v01 = (g & 1) ? vnt[1] : vnt[0];
        float v23 = (g & 1) ? vnt[3] : vnt[2];
        float val = (g & 2) ? v23 : v01;
        size_t o = (size_t)p * 128 + nh * 64 + t;
        out[o] = val;
        out[o + OUT_HALF] = val;
    }
}

extern "C" void kernel_launch(void* const* d_in, const int* in_sizes, int n_in,
                              void* d_out, int out_size, void* d_ws, size_t ws_size,
                              hipStream_t stream) {
    const float* xyz_proj    = (const float*)d_in[0];
    const float* points_proj = (const float*)d_in[1];
    const float* xyz_sampled = (const float*)d_in[2];
    const int*   neighbor_idx= (const int*)  d_in[3];
    const float* valid_mask  = (const float*)d_in[4];
    const float* W0 = (const float*)d_in[5];
    const float* b0 = (const float*)d_in[6];
    const float* g0 = (const float*)d_in[7];
    const float* be0= (const float*)d_in[8];
    const float* W1 = (const float*)d_in[9];
    const float* b1 = (const float*)d_in[10];
    const float* g1 = (const float*)d_in[11];
    const float* be1= (const float*)d_in[12];
    const float* W2 = (const float*)d_in[13];
    const float* b2 = (const float*)d_in[14];
    const float* g2 = (const float*)d_in[15];
    const float* be2= (const float*)d_in[16];

    uint16_t* ws = (uint16_t*)d_ws;

    prep_weights<<<64, 256, 0, stream>>>(W0, b0, g0, be0,
                                         W1, b1, g1, be1,
                                         W2, b2, g2, be2, ws);

    pointnet_mfma<<<8192, 256, 0, stream>>>(
        xyz_proj, points_proj, xyz_sampled, neighbor_idx, valid_mask,
        ws, (float*)d_out);
}

// Round 9
// 135.471 us; speedup vs baseline: 2.3420x; 1.0711x over previous
//
#include <hip/hip_runtime.h>
#include <stdint.h>

// Problem constants
#define NN 16384                  // sampled points per batch (h*w)
#define HW 65536                  // H*W
#define OUT_HALF (2 * NN * 128)   // one tuple element, flat floats
// MLP: 67 -> 64 -> 64 -> 128 (BN folded), maxpool over K=32 neighbors.
//
// Round-9 structure: 32x32x16 bf16 MFMA, one wave = TWO points (M = 64 as
// two 32-row m-tiles, one tile per point). Rationale (r8 post-mortem):
// kernel is instruction-issue bound; 32x32 MFMA cuts MFMA instrs 216->102
// per point, 2-point packing halves weight loads per point (72->34), bias
// folds into acc init. The 32-row m-tile == the 32 neighbors, so gather
// addressing, mask, and xyz all use the lane's OWN registers (no shuffles).
// fp32 accuracy via hi/lo bf16 split, 3 passes: ah*wh + al*wh + ah*wl.
// No __syncthreads (waves independent); intra-wave LDS RAW ordering via
// s_waitcnt lgkmcnt(0) + sched_barrier (rule #18).
// LDS: 2 waves x 2 point-tiles x 8 KiB = 32 KiB/block -> 5 blocks/CU
// (10 waves/CU cap -> VGPR growth up to ~200 is occupancy-free).
//
// Fragment maps (gfx950 32x32x16 bf16):
//   A: row = lane&31, k = 8*(lane>>5)+e   (e = 0..7; 4 VGPRs)
//   B: col = lane&31, k = 8*(lane>>5)+e
//   C/D: col = lane&31, row = (reg&3) + 8*(reg>>2) + 4*(lane>>5)
//        [m74/m101-verified]

typedef __attribute__((ext_vector_type(8)))  short bf16x8;
typedef __attribute__((ext_vector_type(16))) float f32x16;

// ws layout, uint16 units:
//  L0 hi @ 0      [5 kt][2 nt][64 lane][8 e]  (5120)
//  L0 lo @ 5120
//  L1 hi @ 10240  [4][2][64][8]               (4096)
//  L1 lo @ 14336
//  L2 hi @ 18432  [4][4][64][8]               (8192)
//  L2 lo @ 26624
//  bias  @ 34816  f32[256]: bias0[64], bias1[64], bias2[128]
#define WS_L0H 0
#define WS_L0L 5120
#define WS_L1H 10240
#define WS_L1L 14336
#define WS_L2H 18432
#define WS_L2L 26624
#define WS_BIAS 34816

__device__ inline uint16_t f32_to_bf16_rne(float x) {
    uint32_t u = __float_as_uint(x);
    uint32_t r = (u + 0x7FFFu + ((u >> 16) & 1u)) >> 16;
    return (uint16_t)r;
}
__device__ inline float bf16_hi_f32(uint16_t h) {
    return __uint_as_float(((uint32_t)h) << 16);
}
__device__ inline void split2(float v, uint16_t* hi, uint16_t* lo) {
    uint16_t h = f32_to_bf16_rne(v);
    *hi = h;
    *lo = f32_to_bf16_rne(v - bf16_hi_f32(h));
}

// ---------------- weight prep (runs once per launch, tiny) ----------------
// L0 K order: k 0..63 -> points channel k (W0 row 3+k); k 64..66 -> xyz
// (W0 rows 0..2); k 67..79 -> zero pad.  k = kt*16 + 8*(lane>>5) + e.
__global__ void prep_weights(
    const float* __restrict__ W0, const float* __restrict__ b0,
    const float* __restrict__ g0, const float* __restrict__ be0,
    const float* __restrict__ W1, const float* __restrict__ b1,
    const float* __restrict__ g1, const float* __restrict__ be1,
    const float* __restrict__ W2, const float* __restrict__ b2,
    const float* __restrict__ g2, const float* __restrict__ be2,
    uint16_t* __restrict__ ws)
{
    const int tid = blockIdx.x * blockDim.x + threadIdx.x;
    const int nth = gridDim.x * blockDim.x;

    // L0: [5 kt][2 nt][64 lane][8 e]
    for (int i = tid; i < 5120; i += nth) {
        int e = i & 7, lane = (i >> 3) & 63, nt = (i >> 9) & 1, kt = i >> 10;
        int k = kt * 16 + 8 * (lane >> 5) + e;
        int n = nt * 32 + (lane & 31);
        float v = 0.f;
        if (k < 64)       v = W0[(3 + k) * 64 + n] * g0[n];
        else if (k < 67)  v = W0[(k - 64) * 64 + n] * g0[n];
        uint16_t hi, lo; split2(v, &hi, &lo);
        ws[WS_L0H + i] = hi; ws[WS_L0L + i] = lo;
    }
    // L1: [4 kt][2 nt][64][8]
    for (int i = tid; i < 4096; i += nth) {
        int e = i & 7, lane = (i >> 3) & 63, nt = (i >> 9) & 1, kt = i >> 10;
        int k = kt * 16 + 8 * (lane >> 5) + e;
        int n = nt * 32 + (lane & 31);
        float v = W1[k * 64 + n] * g1[n];
        uint16_t hi, lo; split2(v, &hi, &lo);
        ws[WS_L1H + i] = hi; ws[WS_L1L + i] = lo;
    }
    // L2: [4 kt][4 nt][64][8]
    for (int i = tid; i < 8192; i += nth) {
        int e = i & 7, lane = (i >> 3) & 63, nt = (i >> 9) & 3, kt = i >> 11;
        int k = kt * 16 + 8 * (lane >> 5) + e;
        int n = nt * 32 + (lane & 31);
        float v = W2[k * 128 + n] * g2[n];
        uint16_t hi, lo; split2(v, &hi, &lo);
        ws[WS_L2H + i] = hi; ws[WS_L2L + i] = lo;
    }
    float* bias = (float*)(ws + WS_BIAS);
    for (int i = tid; i < 64; i += nth)  bias[i]       = b0[i] * g0[i] + be0[i];
    for (int i = tid; i < 64; i += nth)  bias[64 + i]  = b1[i] * g1[i] + be1[i];
    for (int i = tid; i < 128; i += nth) bias[128 + i] = b2[i] * g2[i] + be2[i];
}

// ---------------- main kernel helpers ----------------
__device__ inline uint32_t cvt_pk_bf16(float a, float b) {
    uint32_t r;
    asm("v_cvt_pk_bf16_f32 %0, %1, %2" : "=v"(r) : "v"(a), "v"(b));
    return r;
}

union frag_u { uint32_t w[4]; bf16x8 v; };

// split 8 f32 -> hi/lo bf16x8 via packed converts (lo = a - f32(hi), exact)
__device__ inline void split8(const float* f, bf16x8* hi, bf16x8* lo) {
    frag_u H, L;
    #pragma unroll
    for (int p2 = 0; p2 < 4; ++p2) {
        float a = f[2 * p2], b = f[2 * p2 + 1];
        uint32_t h = cvt_pk_bf16(a, b);
        float ha = __uint_as_float(h << 16);
        float hb = __uint_as_float(h & 0xffff0000u);
        uint32_t l = cvt_pk_bf16(a - ha, b - hb);
        H.w[p2] = h; L.w[p2] = l;
    }
    *hi = H.v; *lo = L.v;
}

__device__ inline f32x16 mfma3(bf16x8 ah, bf16x8 al, bf16x8 wh, bf16x8 wl, f32x16 c) {
    c = __builtin_amdgcn_mfma_f32_32x32x16_bf16(ah, wh, c, 0, 0, 0);
    c = __builtin_amdgcn_mfma_f32_32x32x16_bf16(al, wh, c, 0, 0, 0);
    c = __builtin_amdgcn_mfma_f32_32x32x16_bf16(ah, wl, c, 0, 0, 0);
    return c;
}

// swizzled f32 tile [32][64]: elem = row*64 + (col ^ ((row&7)<<2))
__device__ inline void load_frag(const float* tile, int row, int c0, float* f) {
    const int sw = (row & 7) << 2;
    *(float4*)&f[0] = *(const float4*)&tile[row * 64 + (c0 ^ sw)];
    *(float4*)&f[4] = *(const float4*)&tile[row * 64 + ((c0 + 4) ^ sw)];
}

#define WAVE_LDS_FENCE() do { \
    asm volatile("s_waitcnt lgkmcnt(0)" ::: "memory"); \
    __builtin_amdgcn_sched_barrier(0); \
} while (0)

__global__ __launch_bounds__(128)
void pointnet_mfma(
    const float* __restrict__ xyz_proj,      // [B, H*W, 3]
    const float* __restrict__ points_proj,   // [B, H*W, 64]
    const float* __restrict__ xyz_sampled,   // [B, N, 3]
    const int*   __restrict__ nidx,          // [B, N, 32]
    const float* __restrict__ vmask,         // [B, N, 32, 1]
    const uint16_t* __restrict__ wf,
    float* __restrict__ out)
{
    __shared__ float s_feat[2][2][2048];     // [wave][point][32*64] = 32 KiB

    // XCD-aware bijective swizzle (grid 8192, 8 XCDs, 1024 blocks per XCD)
    const int bid = blockIdx.x;
    const int swz = (bid & 7) * 1024 + (bid >> 3);

    const int t     = threadIdx.x & 63;
    const int widx  = threadIdx.x >> 6;
    const int pbase = swz * 4 + widx * 2;    // 2 points per wave, 4 per block
    const int rb    = (pbase >> 14) << 16;   // b * HW (pair never crosses batch)

    float* tile0 = s_feat[widx][0];
    float* tile1 = s_feat[widx][1];

    const bf16x8* L0h = (const bf16x8*)(wf + WS_L0H);
    const bf16x8* L0l = (const bf16x8*)(wf + WS_L0L);
    const bf16x8* L1h = (const bf16x8*)(wf + WS_L1H);
    const bf16x8* L1l = (const bf16x8*)(wf + WS_L1L);
    const bf16x8* L2h = (const bf16x8*)(wf + WS_L2H);
    const bf16x8* L2l = (const bf16x8*)(wf + WS_L2L);
    const float*  bias = (const float*)(wf + WS_BIAS);

    const int r  = t & 31;   // neighbor row (A-frag row = lane's own neighbor)
    const int kh = t >> 5;   // k-half selector

    // ---- per-neighbor scalars, both points (lanes' own registers) ----
    const int   idx0 = nidx[(size_t)(pbase + 0) * 32 + r];
    const float m0   = vmask[(size_t)(pbase + 0) * 32 + r];
    const int   idx1 = nidx[(size_t)(pbase + 1) * 32 + r];
    const float m1   = vmask[(size_t)(pbase + 1) * 32 + r];

    float xd0_0, xd0_1, xd0_2, xd1_0, xd1_1, xd1_2;
    {
        const float* xs0 = xyz_proj + (size_t)(rb + idx0) * 3;
        const float* xs1 = xyz_proj + (size_t)(rb + idx1) * 3;
        const float* ns0 = xyz_sampled + (size_t)(pbase + 0) * 3;
        const float* ns1 = xyz_sampled + (size_t)(pbase + 1) * 3;
        xd0_0 = xs0[0] * m0 - ns0[0];
        xd0_1 = xs0[1] * m0 - ns0[1];
        xd0_2 = xs0[2] * m0 - ns0[2];
        xd1_0 = xs1[0] * m1 - ns1[0];
        xd1_1 = xs1[1] * m1 - ns1[1];
        xd1_2 = xs1[2] * m1 - ns1[2];
    }

    const float* rowp0 = points_proj + (size_t)(rb + idx0) * 64 + 8 * kh;
    const float* rowp1 = points_proj + (size_t)(rb + idx1) * 64 + 8 * kh;

    // ---- layer 0: K = 64 (channels) + 3 (xyz) -> 64 ----
    f32x16 acc0[2][2];
    {
        float bb0 = bias[r], bb1 = bias[32 + r];
        #pragma unroll
        for (int i = 0; i < 16; ++i) {
            acc0[0][0][i] = bb0; acc0[1][0][i] = bb0;
            acc0[0][1][i] = bb1; acc0[1][1][i] = bb1;
        }
    }
    #pragma unroll
    for (int kt = 0; kt < 4; ++kt) {
        bf16x8 wh[2], wl[2];
        #pragma unroll
        for (int nt = 0; nt < 2; ++nt) {
            wh[nt] = L0h[(kt * 2 + nt) * 64 + t];
            wl[nt] = L0l[(kt * 2 + nt) * 64 + t];
        }
        bf16x8 ah[2], al[2];
        #pragma unroll
        for (int mt = 0; mt < 2; ++mt) {
            const float* rp = (mt ? rowp1 : rowp0) + kt * 16;
            const float mm  = mt ? m1 : m0;
            float f[8];
            *(float4*)&f[0] = ((const float4*)rp)[0];
            *(float4*)&f[4] = ((const float4*)rp)[1];
            #pragma unroll
            for (int e = 0; e < 8; ++e) f[e] *= mm;
            split8(f, &ah[mt], &al[mt]);
        }
        #pragma unroll
        for (int nt = 0; nt < 2; ++nt)
            #pragma unroll
            for (int mt = 0; mt < 2; ++mt)
                acc0[mt][nt] = mfma3(ah[mt], al[mt], wh[nt], wl[nt], acc0[mt][nt]);
    }
    {   // kt = 4: xyz k-step (k 64..66 live in kh==0, e<3; rest zero)
        bf16x8 wh[2], wl[2];
        #pragma unroll
        for (int nt = 0; nt < 2; ++nt) {
            wh[nt] = L0h[(8 + nt) * 64 + t];
            wl[nt] = L0l[(8 + nt) * 64 + t];
        }
        const bool lo32 = (kh == 0);
        float f0[8] = { lo32 ? xd0_0 : 0.f, lo32 ? xd0_1 : 0.f, lo32 ? xd0_2 : 0.f,
                        0.f, 0.f, 0.f, 0.f, 0.f };
        float f1[8] = { lo32 ? xd1_0 : 0.f, lo32 ? xd1_1 : 0.f, lo32 ? xd1_2 : 0.f,
                        0.f, 0.f, 0.f, 0.f, 0.f };
        bf16x8 ah[2], al[2];
        split8(f0, &ah[0], &al[0]);
        split8(f1, &ah[1], &al[1]);
        #pragma unroll
        for (int nt = 0; nt < 2; ++nt)
            #pragma unroll
            for (int mt = 0; mt < 2; ++mt)
                acc0[mt][nt] = mfma3(ah[mt], al[mt], wh[nt], wl[nt], acc0[mt][nt]);
    }
    {   // relu (bias pre-folded) -> writeback to per-point swizzled tiles
        #pragma unroll
        for (int mt = 0; mt < 2; ++mt) {
            float* tl = mt ? tile1 : tile0;
            #pragma unroll
            for (int nt = 0; nt < 2; ++nt)
                #pragma unroll
                for (int rg = 0; rg < 16; ++rg) {
                    float y = fmaxf(acc0[mt][nt][rg], 0.f);
                    const int row = (rg & 3) + 8 * (rg >> 2) + 4 * kh;
                    const int col = nt * 32 + r;
                    tl[row * 64 + (col ^ ((row & 7) << 2))] = y;
                }
        }
    }

    WAVE_LDS_FENCE();

    // ---- layer 1: 64 -> 64 ----
    f32x16 acc1[2][2];
    {
        float bb0 = bias[64 + r], bb1 = bias[64 + 32 + r];
        #pragma unroll
        for (int i = 0; i < 16; ++i) {
            acc1[0][0][i] = bb0; acc1[1][0][i] = bb0;
            acc1[0][1][i] = bb1; acc1[1][1][i] = bb1;
        }
    }
    #pragma unroll
    for (int kt = 0; kt < 4; ++kt) {
        bf16x8 wh[2], wl[2];
        #pragma unroll
        for (int nt = 0; nt < 2; ++nt) {
            wh[nt] = L1h[(kt * 2 + nt) * 64 + t];
            wl[nt] = L1l[(kt * 2 + nt) * 64 + t];
        }
        bf16x8 ah[2], al[2];
        #pragma unroll
        for (int mt = 0; mt < 2; ++mt) {
            const float* tl = mt ? tile1 : tile0;
            float f[8];
            load_frag(tl, r, kt * 16 + 8 * kh, f);
            split8(f, &ah[mt], &al[mt]);
        }
        #pragma unroll
        for (int nt = 0; nt < 2; ++nt)
            #pragma unroll
            for (int mt = 0; mt < 2; ++mt)
                acc1[mt][nt] = mfma3(ah[mt], al[mt], wh[nt], wl[nt], acc1[mt][nt]);
    }
    {
        #pragma unroll
        for (int mt = 0; mt < 2; ++mt) {
            float* tl = mt ? tile1 : tile0;
            #pragma unroll
            for (int nt = 0; nt < 2; ++nt)
                #pragma unroll
                for (int rg = 0; rg < 16; ++rg) {
                    float y = fmaxf(acc1[mt][nt][rg], 0.f);
                    const int row = (rg & 3) + 8 * (rg >> 2) + 4 * kh;
                    const int col = nt * 32 + r;
                    tl[row * 64 + (col ^ ((row & 7) << 2))] = y;
                }
        }
    }

    WAVE_LDS_FENCE();

    // ---- layer 2: 64 -> 128 (two 64-col halves), fused maxpool + store ----
    #pragma unroll
    for (int nh = 0; nh < 2; ++nh) {
        f32x16 acc2[2][2];
        {
            float bb0 = bias[128 + (nh * 2 + 0) * 32 + r];
            float bb1 = bias[128 + (nh * 2 + 1) * 32 + r];
            #pragma unroll
            for (int i = 0; i < 16; ++i) {
                acc2[0][0][i] = bb0; acc2[1][0][i] = bb0;
                acc2[0][1][i] = bb1; acc2[1][1][i] = bb1;
            }
        }
        #pragma unroll
        for (int kt = 0; kt < 4; ++kt) {
            bf16x8 wh[2], wl[2];
            #pragma unroll
            for (int j = 0; j < 2; ++j) {
                wh[j] = L2h[(kt * 4 + nh * 2 + j) * 64 + t];
                wl[j] = L2l[(kt * 4 + nh * 2 + j) * 64 + t];
            }
            bf16x8 ah[2], al[2];
            #pragma unroll
            for (int mt = 0; mt < 2; ++mt) {
                const float* tl = mt ? tile1 : tile0;
                float f[8];
                load_frag(tl, r, kt * 16 + 8 * kh, f);
                split8(f, &ah[mt], &al[mt]);
            }
            #pragma unroll
            for (int j = 0; j < 2; ++j)
                #pragma unroll
                for (int mt = 0; mt < 2; ++mt)
                    acc2[mt][j] = mfma3(ah[mt], al[mt], wh[j], wl[j], acc2[mt][j]);
        }
        // maxpool over 32 neighbors: 16 regs cover half the rows; xor(32)
        // merges the complementary kh half. Then relu; store per point.
        #pragma unroll
        for (int j = 0; j < 2; ++j) {
            float v0 = acc2[0][j][0], v1 = acc2[1][j][0];
            #pragma unroll
            for (int rg = 1; rg < 16; ++rg) {
                v0 = fmaxf(v0, acc2[0][j][rg]);
                v1 = fmaxf(v1, acc2[1][j][rg]);
            }
            v0 = fmaxf(fmaxf(v0, __shfl_xor(v0, 32)), 0.f);
            v1 = fmaxf(fmaxf(v1, __shfl_xor(v1, 32)), 0.f);
            const float val = kh ? v1 : v0;      // lane stores its half's point
            size_t o = (size_t)(pbase + kh) * 128 + (nh * 2 + j) * 32 + r;
            out[o] = val;
            out[o + OUT_HALF] = val;
        }
    }
}

extern "C" void kernel_launch(void* const* d_in, const int* in_sizes, int n_in,
                              void* d_out, int out_size, void* d_ws, size_t ws_size,
                              hipStream_t stream) {
    const float* xyz_proj    = (const float*)d_in[0];
    const float* points_proj = (const float*)d_in[1];
    const float* xyz_sampled = (const float*)d_in[2];
    const int*   neighbor_idx= (const int*)  d_in[3];
    const float* valid_mask  = (const float*)d_in[4];
    const float* W0 = (const float*)d_in[5];
    const float* b0 = (const float*)d_in[6];
    const float* g0 = (const float*)d_in[7];
    const float* be0= (const float*)d_in[8];
    const float* W1 = (const float*)d_in[9];
    const float* b1 = (const float*)d_in[10];
    const float* g1 = (const float*)d_in[11];
    const float* be1= (const float*)d_in[12];
    const float* W2 = (const float*)d_in[13];
    const float* b2 = (const float*)d_in[14];
    const float* g2 = (const float*)d_in[15];
    const float* be2= (const float*)d_in[16];

    uint16_t* ws = (uint16_t*)d_ws;

    prep_weights<<<64, 256, 0, stream>>>(W0, b0, g0, be0,
                                         W1, b1, g1, be1,
                                         W2, b2, g2, be2, ws);

    // 32768 points: 2 per wave, 2 waves per block -> 8192 blocks
    pointnet_mfma<<<8192, 128, 0, stream>>>(
        xyz_proj, points_proj, xyz_sampled, neighbor_idx, valid_mask,
        ws, (float*)d_out);
}

// Round 10
// 133.472 us; speedup vs baseline: 2.3771x; 1.0150x over previous
//
#include <hip/hip_runtime.h>
#include <stdint.h>

// Problem constants
#define NN 16384                  // sampled points per batch (h*w)
#define HW 65536                  // H*W
#define OUT_HALF (2 * NN * 128)   // one tuple element, flat floats
// MLP: 67 -> 64 -> 64 -> 128 (BN folded), maxpool over K=32 neighbors.
//
// Round-10 structure: ZERO LDS. One wave = one point, 32x32x16 bf16 MFMA.
// L0/L1 run OPERAND-SWAPPED (A = weights [ch_out x ch_in], B = activations
// [ch_in x neighbor]) so C/D col = lane&31 = neighbor: the same lane owns the
// same neighbor all the way through. Layer transitions are pure in-register:
// relu -> cvt_pk hi/lo split -> v_permlane32_swap_b32 exchanges the kh-half
// quads, directly assembling next layer's K-fragments (B for L1; identical
// per-lane layout serves as A for L2). L2 flips back (A = act, B = W2) so
// C/D col = ch_out and maxpool is 16 fmax + one xor(32) shuffle; the two
// tuple copies are stored by the two kh halves (no divergence).
// fp32 accuracy via hi/lo bf16, 3 passes (hi*hi + lo*hi + hi*lo).
// No __syncthreads, no fences, no bank conflicts; occupancy is VGPR-bound.
//
// Fragment maps (gfx950 32x32x16 bf16):
//   A: row = lane&31, k = 8*(lane>>5)+e ;  B: col = lane&31, same k
//   C/D: col = lane&31, row = (rg&3) + 8*(rg>>2) + 4*(lane>>5)  [m74/m101]
// Transition algebra: C/D row quads per lane: {0-3,8-11,16-19,24-27}+4kh.
// Fragment(kt) for reader kh needs rows 16*(kt&1)+8*kh+0..7 = own quad
// rg[8(kt&1)+4kh ..] + partner's same quad. permlane32_swap(A,B):
// A' = [A_lo, B_lo], B' = [A_hi, B_hi]  ->  with (A,B) = (H[w], H[w+2]):
// A' = frag word w (both halves), B' = frag word w+2 (both halves).

typedef __attribute__((ext_vector_type(8)))  short bf16x8;
typedef __attribute__((ext_vector_type(16))) float f32x16;

// ws layout, uint16 units (identical to round 9; formulas are
// orientation-agnostic: stored value = Wfold[k][tile*32+(lane&31)]):
//  L0 hi @ 0      [5 kt][2 tile][64 lane][8 e]  (5120)
//  L0 lo @ 5120
//  L1 hi @ 10240  [4][2][64][8]               (4096)
//  L1 lo @ 14336
//  L2 hi @ 18432  [4][4][64][8]               (8192)
//  L2 lo @ 26624
//  bias  @ 34816  f32[256]: bias0[64], bias1[64], bias2[128]
#define WS_L0H 0
#define WS_L0L 5120
#define WS_L1H 10240
#define WS_L1L 14336
#define WS_L2H 18432
#define WS_L2L 26624
#define WS_BIAS 34816

__device__ inline uint16_t f32_to_bf16_rne(float x) {
    uint32_t u = __float_as_uint(x);
    uint32_t r = (u + 0x7FFFu + ((u >> 16) & 1u)) >> 16;
    return (uint16_t)r;
}
__device__ inline float bf16_hi_f32(uint16_t h) {
    return __uint_as_float(((uint32_t)h) << 16);
}
__device__ inline void split2(float v, uint16_t* hi, uint16_t* lo) {
    uint16_t h = f32_to_bf16_rne(v);
    *hi = h;
    *lo = f32_to_bf16_rne(v - bf16_hi_f32(h));
}

// ---------------- weight prep (runs once per launch, tiny) ----------------
// L0 K order: k 0..63 -> points channel k (W0 row 3+k); k 64..66 -> xyz
// (W0 rows 0..2); k 67..79 -> zero pad.  k = kt*16 + 8*(lane>>5) + e.
__global__ void prep_weights(
    const float* __restrict__ W0, const float* __restrict__ b0,
    const float* __restrict__ g0, const float* __restrict__ be0,
    const float* __restrict__ W1, const float* __restrict__ b1,
    const float* __restrict__ g1, const float* __restrict__ be1,
    const float* __restrict__ W2, const float* __restrict__ b2,
    const float* __restrict__ g2, const float* __restrict__ be2,
    uint16_t* __restrict__ ws)
{
    const int tid = blockIdx.x * blockDim.x + threadIdx.x;
    const int nth = gridDim.x * blockDim.x;

    // L0: [5 kt][2 tile][64 lane][8 e]
    for (int i = tid; i < 5120; i += nth) {
        int e = i & 7, lane = (i >> 3) & 63, nt = (i >> 9) & 1, kt = i >> 10;
        int k = kt * 16 + 8 * (lane >> 5) + e;
        int n = nt * 32 + (lane & 31);
        float v = 0.f;
        if (k < 64)       v = W0[(3 + k) * 64 + n] * g0[n];
        else if (k < 67)  v = W0[(k - 64) * 64 + n] * g0[n];
        uint16_t hi, lo; split2(v, &hi, &lo);
        ws[WS_L0H + i] = hi; ws[WS_L0L + i] = lo;
    }
    // L1: [4 kt][2 tile][64][8]
    for (int i = tid; i < 4096; i += nth) {
        int e = i & 7, lane = (i >> 3) & 63, nt = (i >> 9) & 1, kt = i >> 10;
        int k = kt * 16 + 8 * (lane >> 5) + e;
        int n = nt * 32 + (lane & 31);
        float v = W1[k * 64 + n] * g1[n];
        uint16_t hi, lo; split2(v, &hi, &lo);
        ws[WS_L1H + i] = hi; ws[WS_L1L + i] = lo;
    }
    // L2: [4 kt][4 tile][64][8]
    for (int i = tid; i < 8192; i += nth) {
        int e = i & 7, lane = (i >> 3) & 63, nt = (i >> 9) & 3, kt = i >> 11;
        int k = kt * 16 + 8 * (lane >> 5) + e;
        int n = nt * 32 + (lane & 31);
        float v = W2[k * 128 + n] * g2[n];
        uint16_t hi, lo; split2(v, &hi, &lo);
        ws[WS_L2H + i] = hi; ws[WS_L2L + i] = lo;
    }
    float* bias = (float*)(ws + WS_BIAS);
    for (int i = tid; i < 64; i += nth)  bias[i]       = b0[i] * g0[i] + be0[i];
    for (int i = tid; i < 64; i += nth)  bias[64 + i]  = b1[i] * g1[i] + be1[i];
    for (int i = tid; i < 128; i += nth) bias[128 + i] = b2[i] * g2[i] + be2[i];
}

// ---------------- main kernel helpers ----------------
__device__ inline uint32_t cvt_pk_bf16(float a, float b) {
    uint32_t r;
    asm("v_cvt_pk_bf16_f32 %0, %1, %2" : "=v"(r) : "v"(a), "v"(b));
    return r;
}

union frag_u { uint32_t w[4]; bf16x8 v; };

// split 8 f32 -> hi/lo bf16x8 via packed converts (lo = a - f32(hi), exact)
__device__ inline void split8(const float* f, bf16x8* hi, bf16x8* lo) {
    frag_u H, L;
    #pragma unroll
    for (int p2 = 0; p2 < 4; ++p2) {
        float a = f[2 * p2], b = f[2 * p2 + 1];
        uint32_t h = cvt_pk_bf16(a, b);
        float ha = __uint_as_float(h << 16);
        float hb = __uint_as_float(h & 0xffff0000u);
        uint32_t l = cvt_pk_bf16(a - ha, b - hb);
        H.w[p2] = h; L.w[p2] = l;
    }
    *hi = H.v; *lo = L.v;
}

// L0/L1 (swapped): D += W * act
__device__ inline f32x16 mfma3_WA(bf16x8 wh, bf16x8 wl, bf16x8 bh, bf16x8 bl, f32x16 c) {
    c = __builtin_amdgcn_mfma_f32_32x32x16_bf16(wh, bh, c, 0, 0, 0);
    c = __builtin_amdgcn_mfma_f32_32x32x16_bf16(wl, bh, c, 0, 0, 0);
    c = __builtin_amdgcn_mfma_f32_32x32x16_bf16(wh, bl, c, 0, 0, 0);
    return c;
}
// L2 (normal): D += act * W
__device__ inline f32x16 mfma3_AW(bf16x8 ah, bf16x8 al, bf16x8 wh, bf16x8 wl, f32x16 c) {
    c = __builtin_amdgcn_mfma_f32_32x32x16_bf16(ah, wh, c, 0, 0, 0);
    c = __builtin_amdgcn_mfma_f32_32x32x16_bf16(al, wh, c, 0, 0, 0);
    c = __builtin_amdgcn_mfma_f32_32x32x16_bf16(ah, wl, c, 0, 0, 0);
    return c;
}

// relu + hi/lo split + permlane32_swap assembly of next layer's K-fragments.
// acc[2] (C/D, col=neighbor) -> fh/fl[4] (kt-indexed K-fragments).
__device__ inline void transition(const f32x16* acc, bf16x8* fh, bf16x8* fl) {
    #pragma unroll
    for (int mt = 0; mt < 2; ++mt) {
        uint32_t H[8], L[8];
        #pragma unroll
        for (int w = 0; w < 8; ++w) {
            float a = fmaxf(acc[mt][2 * w],     0.f);
            float b = fmaxf(acc[mt][2 * w + 1], 0.f);
            uint32_t h = cvt_pk_bf16(a, b);
            float ha = __uint_as_float(h << 16);
            float hb = __uint_as_float(h & 0xffff0000u);
            H[w] = h;
            L[w] = cvt_pk_bf16(a - ha, b - hb);
        }
        #pragma unroll
        for (int ktL = 0; ktL < 2; ++ktL) {
            uint32_t a0 = H[4 * ktL + 0], b0 = H[4 * ktL + 2];
            uint32_t a1 = H[4 * ktL + 1], b1 = H[4 * ktL + 3];
            asm("v_permlane32_swap_b32 %0, %1" : "+v"(a0), "+v"(b0));
            asm("v_permlane32_swap_b32 %0, %1" : "+v"(a1), "+v"(b1));
            uint32_t c0 = L[4 * ktL + 0], d0 = L[4 * ktL + 2];
            uint32_t c1 = L[4 * ktL + 1], d1 = L[4 * ktL + 3];
            asm("v_permlane32_swap_b32 %0, %1" : "+v"(c0), "+v"(d0));
            asm("v_permlane32_swap_b32 %0, %1" : "+v"(c1), "+v"(d1));
            frag_u F; F.w[0] = a0; F.w[1] = a1; F.w[2] = b0; F.w[3] = b1;
            frag_u G; G.w[0] = c0; G.w[1] = c1; G.w[2] = d0; G.w[3] = d1;
            fh[mt * 2 + ktL] = F.v;
            fl[mt * 2 + ktL] = G.v;
        }
    }
}

__global__ __launch_bounds__(256)
void pointnet_mfma(
    const float* __restrict__ xyz_proj,      // [B, H*W, 3]
    const float* __restrict__ points_proj,   // [B, H*W, 64]
    const float* __restrict__ xyz_sampled,   // [B, N, 3]
    const int*   __restrict__ nidx,          // [B, N, 32]
    const float* __restrict__ vmask,         // [B, N, 32, 1]
    const uint16_t* __restrict__ wf,
    float* __restrict__ out)
{
    // XCD-aware bijective swizzle (grid 8192, 8 XCDs, 1024 blocks per XCD)
    const int bid = blockIdx.x;
    const int swz = (bid & 7) * 1024 + (bid >> 3);

    const int t    = threadIdx.x & 63;
    const int widx = threadIdx.x >> 6;
    const int p    = swz * 4 + widx;          // point id in [0, 2*NN)
    const int rb   = (p >> 14) << 16;          // b * HW

    const int r  = t & 31;   // this lane's neighbor (col) all the way through
    const int kh = t >> 5;   // k-half selector

    const bf16x8* L0h = (const bf16x8*)(wf + WS_L0H);
    const bf16x8* L0l = (const bf16x8*)(wf + WS_L0L);
    const bf16x8* L1h = (const bf16x8*)(wf + WS_L1H);
    const bf16x8* L1l = (const bf16x8*)(wf + WS_L1L);
    const bf16x8* L2h = (const bf16x8*)(wf + WS_L2H);
    const bf16x8* L2l = (const bf16x8*)(wf + WS_L2L);
    const float*  bias = (const float*)(wf + WS_BIAS);

    // ---- per-neighbor scalars (each lane: its own neighbor) ----
    const int   idx = nidx[(size_t)p * 32 + r];
    const float m   = vmask[(size_t)p * 32 + r];
    float xd0, xd1, xd2;
    {
        const float* xs = xyz_proj + (size_t)(rb + idx) * 3;
        const float* ns = xyz_sampled + (size_t)p * 3;
        xd0 = xs[0] * m - ns[0];
        xd1 = xs[1] * m - ns[1];
        xd2 = xs[2] * m - ns[2];
    }
    const float* rowp = points_proj + (size_t)(rb + idx) * 64 + 8 * kh;

    // ---- layer 0: K = 64 (channels) + 3 (xyz) -> 64, swapped (W=A) ----
    f32x16 acc0[2];
    #pragma unroll
    for (int mt = 0; mt < 2; ++mt)
        #pragma unroll
        for (int q = 0; q < 4; ++q) {
            float4 bq = *(const float4*)(bias + mt * 32 + 4 * kh + 8 * q);
            acc0[mt][4 * q + 0] = bq.x; acc0[mt][4 * q + 1] = bq.y;
            acc0[mt][4 * q + 2] = bq.z; acc0[mt][4 * q + 3] = bq.w;
        }
    #pragma unroll
    for (int kt = 0; kt < 4; ++kt) {
        bf16x8 wh0 = L0h[(kt * 2 + 0) * 64 + t], wl0 = L0l[(kt * 2 + 0) * 64 + t];
        bf16x8 wh1 = L0h[(kt * 2 + 1) * 64 + t], wl1 = L0l[(kt * 2 + 1) * 64 + t];
        float f[8];
        *(float4*)&f[0] = ((const float4*)(rowp + kt * 16))[0];
        *(float4*)&f[4] = ((const float4*)(rowp + kt * 16))[1];
        #pragma unroll
        for (int e = 0; e < 8; ++e) f[e] *= m;
        bf16x8 bh, bl; split8(f, &bh, &bl);
        acc0[0] = mfma3_WA(wh0, wl0, bh, bl, acc0[0]);
        acc0[1] = mfma3_WA(wh1, wl1, bh, bl, acc0[1]);
    }
    {   // kt = 4: xyz k-step (k 64..66 live in kh==0 lanes, e<3)
        bf16x8 wh0 = L0h[(8 + 0) * 64 + t], wl0 = L0l[(8 + 0) * 64 + t];
        bf16x8 wh1 = L0h[(8 + 1) * 64 + t], wl1 = L0l[(8 + 1) * 64 + t];
        const bool lo32 = (kh == 0);
        float f[8] = { lo32 ? xd0 : 0.f, lo32 ? xd1 : 0.f, lo32 ? xd2 : 0.f,
                       0.f, 0.f, 0.f, 0.f, 0.f };
        bf16x8 bh, bl; split8(f, &bh, &bl);
        acc0[0] = mfma3_WA(wh0, wl0, bh, bl, acc0[0]);
        acc0[1] = mfma3_WA(wh1, wl1, bh, bl, acc0[1]);
    }

    // ---- transition 1: in-register relu+split+swap -> L1 B-fragments ----
    bf16x8 fh[4], fl[4];
    transition(acc0, fh, fl);

    // ---- layer 1: 64 -> 64, swapped (W=A) ----
    f32x16 acc1[2];
    #pragma unroll
    for (int mt = 0; mt < 2; ++mt)
        #pragma unroll
        for (int q = 0; q < 4; ++q) {
            float4 bq = *(const float4*)(bias + 64 + mt * 32 + 4 * kh + 8 * q);
            acc1[mt][4 * q + 0] = bq.x; acc1[mt][4 * q + 1] = bq.y;
            acc1[mt][4 * q + 2] = bq.z; acc1[mt][4 * q + 3] = bq.w;
        }
    #pragma unroll
    for (int kt = 0; kt < 4; ++kt) {
        bf16x8 wh0 = L1h[(kt * 2 + 0) * 64 + t], wl0 = L1l[(kt * 2 + 0) * 64 + t];
        bf16x8 wh1 = L1h[(kt * 2 + 1) * 64 + t], wl1 = L1l[(kt * 2 + 1) * 64 + t];
        acc1[0] = mfma3_WA(wh0, wl0, fh[kt], fl[kt], acc1[0]);
        acc1[1] = mfma3_WA(wh1, wl1, fh[kt], fl[kt], acc1[1]);
    }

    // ---- transition 2 -> L2 A-fragments (same per-lane layout) ----
    bf16x8 gh[4], gl[4];
    transition(acc1, gh, gl);

    // ---- layer 2: 64 -> 128, normal (act=A); fused maxpool + store ----
    #pragma unroll
    for (int half = 0; half < 2; ++half) {
        f32x16 acc2[2];
        const float bb0 = bias[128 + (half * 2 + 0) * 32 + r];
        const float bb1 = bias[128 + (half * 2 + 1) * 32 + r];
        #pragma unroll
        for (int i = 0; i < 16; ++i) { acc2[0][i] = bb0; acc2[1][i] = bb1; }
        #pragma unroll
        for (int kt = 0; kt < 4; ++kt) {
            bf16x8 wh0 = L2h[(kt * 4 + half * 2 + 0) * 64 + t];
            bf16x8 wl0 = L2l[(kt * 4 + half * 2 + 0) * 64 + t];
            bf16x8 wh1 = L2h[(kt * 4 + half * 2 + 1) * 64 + t];
            bf16x8 wl1 = L2l[(kt * 4 + half * 2 + 1) * 64 + t];
            acc2[0] = mfma3_AW(gh[kt], gl[kt], wh0, wl0, acc2[0]);
            acc2[1] = mfma3_AW(gh[kt], gl[kt], wh1, wl1, acc2[1]);
        }
        #pragma unroll
        for (int j = 0; j < 2; ++j) {
            float v = acc2[j][0];
            #pragma unroll
            for (int g = 1; g < 16; ++g) v = fmaxf(v, acc2[j][g]);
            v = fmaxf(v, __shfl_xor(v, 32));   // merge kh halves (rows 4..7 etc.)
            v = fmaxf(v, 0.f);                 // relu commutes with max
            // kh=0 lanes store tuple copy 0, kh=1 lanes store copy 1
            size_t o = (size_t)p * 128 + (half * 2 + j) * 32 + r
                     + (size_t)kh * OUT_HALF;
            out[o] = v;
        }
    }
}

extern "C" void kernel_launch(void* const* d_in, const int* in_sizes, int n_in,
                              void* d_out, int out_size, void* d_ws, size_t ws_size,
                              hipStream_t stream) {
    const float* xyz_proj    = (const float*)d_in[0];
    const float* points_proj = (const float*)d_in[1];
    const float* xyz_sampled = (const float*)d_in[2];
    const int*   neighbor_idx= (const int*)  d_in[3];
    const float* valid_mask  = (const float*)d_in[4];
    const float* W0 = (const float*)d_in[5];
    const float* b0 = (const float*)d_in[6];
    const float* g0 = (const float*)d_in[7];
    const float* be0= (const float*)d_in[8];
    const float* W1 = (const float*)d_in[9];
    const float* b1 = (const float*)d_in[10];
    const float* g1 = (const float*)d_in[11];
    const float* be1= (const float*)d_in[12];
    const float* W2 = (const float*)d_in[13];
    const float* b2 = (const float*)d_in[14];
    const float* g2 = (const float*)d_in[15];
    const float* be2= (const float*)d_in[16];

    uint16_t* ws = (uint16_t*)d_ws;

    prep_weights<<<64, 256, 0, stream>>>(W0, b0, g0, be0,
                                         W1, b1, g1, be1,
                                         W2, b2, g2, be2, ws);

    // 32768 points: 1 per wave, 4 waves per block -> 8192 blocks
    pointnet_mfma<<<8192, 256, 0, stream>>>(
        xyz_proj, points_proj, xyz_sampled, neighbor_idx, valid_mask,
        ws, (float*)d_out);
}

// Round 11
// 113.375 us; speedup vs baseline: 2.7985x; 1.1773x over previous
//
#include <hip/hip_runtime.h>
#include <stdint.h>

// Problem constants
#define NN 16384                  // sampled points per batch (h*w)
#define HW 65536                  // H*W
#define OUT_HALF (2 * NN * 128)   // one tuple element, flat floats
// MLP: 67 -> 64 -> 64 -> 128 (BN folded), maxpool over K=32 neighbors.
//
// Round-11 structure: round-10's zero-LDS in-register dataflow, PLUS the hot
// weights staged in LDS. Rationale (r10 post-mortem): 68 weight loads/point
// x 1KB/wave = 2.2 GB/dispatch of L2 traffic (~48% of L2 peak) because the
// 68KB hot set exceeds the 32KB L1 -- weight latency was the unhidden stall.
// LDS-resident part = exactly 64 KiB (L0 kt0-3 + L1 + L2, hi+lo), filled
// cooperatively once per 512-thread block, then ONE __syncthreads; waves
// independent afterwards. Weight reads become conflict-free ds_read_b128
// (16B/lane contiguous), off the vmcnt/L2 path. xyz-step weights (4KB) and
// bias stay in global. 2 blocks/CU (128KB LDS) -> 16 waves/CU cap.
//
// Dataflow (r10, m74/m101-verified maps):
//   L0/L1 operand-swapped (A=W, B=act) -> C/D col = lane&31 = neighbor.
//   Transitions in-register: relu -> cvt_pk hi/lo split -> permlane32_swap.
//   L2 normal (A=act, B=W); maxpool = 16 fmax + xor(32); kh halves store the
//   two tuple copies. fp32 accuracy: 3-pass hi/lo bf16 (hh + lh + hl).
//
// Fragment maps (gfx950 32x32x16 bf16):
//   A: row = lane&31, k = 8*(lane>>5)+e ;  B: col = lane&31, same k
//   C/D: col = lane&31, row = (rg&3) + 8*(rg>>2) + 4*(lane>>5)

typedef __attribute__((ext_vector_type(8)))  short bf16x8;
typedef __attribute__((ext_vector_type(16))) float f32x16;

// ws layout, uint16 units.  LDS-resident block = first 32768 (64 KiB):
//  L0 hi (kt 0..3) @ 0      [4 kt][2 tile][64 lane][8 e] = 4096
//  L0 lo           @ 4096
//  L1 hi           @ 8192   [4][2][64][8] = 4096
//  L1 lo           @ 12288
//  L2 hi           @ 16384  [4][4][64][8] = 8192
//  L2 lo           @ 24576
// Global-only tail:
//  L0 xyz-step hi  @ 32768  [2 tile][64][8] = 1024
//  L0 xyz-step lo  @ 33792
//  bias            @ 34816  f32[256]: bias0[64], bias1[64], bias2[128]
#define WS_L0H 0
#define WS_L0L 4096
#define WS_L1H 8192
#define WS_L1L 12288
#define WS_L2H 16384
#define WS_L2L 24576
#define WS_X0H 32768
#define WS_X0L 33792
#define WS_BIAS 34816
#define LDS_U16 32768            // 64 KiB resident in LDS

__device__ inline uint16_t f32_to_bf16_rne(float x) {
    uint32_t u = __float_as_uint(x);
    uint32_t r = (u + 0x7FFFu + ((u >> 16) & 1u)) >> 16;
    return (uint16_t)r;
}
__device__ inline float bf16_hi_f32(uint16_t h) {
    return __uint_as_float(((uint32_t)h) << 16);
}
__device__ inline void split2(float v, uint16_t* hi, uint16_t* lo) {
    uint16_t h = f32_to_bf16_rne(v);
    *hi = h;
    *lo = f32_to_bf16_rne(v - bf16_hi_f32(h));
}

// ---------------- weight prep (runs once per launch, tiny) ----------------
// L0 K order: k 0..63 -> points channel k (W0 row 3+k); k 64..66 -> xyz
// (W0 rows 0..2).  k = kt*16 + 8*(lane>>5) + e.
__global__ void prep_weights(
    const float* __restrict__ W0, const float* __restrict__ b0,
    const float* __restrict__ g0, const float* __restrict__ be0,
    const float* __restrict__ W1, const float* __restrict__ b1,
    const float* __restrict__ g1, const float* __restrict__ be1,
    const float* __restrict__ W2, const float* __restrict__ b2,
    const float* __restrict__ g2, const float* __restrict__ be2,
    uint16_t* __restrict__ ws)
{
    const int tid = blockIdx.x * blockDim.x + threadIdx.x;
    const int nth = gridDim.x * blockDim.x;

    // L0 main: [4 kt][2 tile][64 lane][8 e], k = kt*16 + 8*kh + e (0..63)
    for (int i = tid; i < 4096; i += nth) {
        int e = i & 7, lane = (i >> 3) & 63, nt = (i >> 9) & 1, kt = i >> 10;
        int k = kt * 16 + 8 * (lane >> 5) + e;
        int n = nt * 32 + (lane & 31);
        float v = W0[(3 + k) * 64 + n] * g0[n];
        uint16_t hi, lo; split2(v, &hi, &lo);
        ws[WS_L0H + i] = hi; ws[WS_L0L + i] = lo;
    }
    // L0 xyz step: [2 tile][64][8], k = 64 + 8*kh + e (valid when kh==0, e<3)
    for (int i = tid; i < 1024; i += nth) {
        int e = i & 7, lane = (i >> 3) & 63, nt = i >> 9;
        int k = 64 + 8 * (lane >> 5) + e;
        int n = nt * 32 + (lane & 31);
        float v = (k < 67) ? W0[(k - 64) * 64 + n] * g0[n] : 0.f;
        uint16_t hi, lo; split2(v, &hi, &lo);
        ws[WS_X0H + i] = hi; ws[WS_X0L + i] = lo;
    }
    // L1: [4 kt][2 tile][64][8]
    for (int i = tid; i < 4096; i += nth) {
        int e = i & 7, lane = (i >> 3) & 63, nt = (i >> 9) & 1, kt = i >> 10;
        int k = kt * 16 + 8 * (lane >> 5) + e;
        int n = nt * 32 + (lane & 31);
        float v = W1[k * 64 + n] * g1[n];
        uint16_t hi, lo; split2(v, &hi, &lo);
        ws[WS_L1H + i] = hi; ws[WS_L1L + i] = lo;
    }
    // L2: [4 kt][4 tile][64][8]
    for (int i = tid; i < 8192; i += nth) {
        int e = i & 7, lane = (i >> 3) & 63, nt = (i >> 9) & 3, kt = i >> 11;
        int k = kt * 16 + 8 * (lane >> 5) + e;
        int n = nt * 32 + (lane & 31);
        float v = W2[k * 128 + n] * g2[n];
        uint16_t hi, lo; split2(v, &hi, &lo);
        ws[WS_L2H + i] = hi; ws[WS_L2L + i] = lo;
    }
    float* bias = (float*)(ws + WS_BIAS);
    for (int i = tid; i < 64; i += nth)  bias[i]       = b0[i] * g0[i] + be0[i];
    for (int i = tid; i < 64; i += nth)  bias[64 + i]  = b1[i] * g1[i] + be1[i];
    for (int i = tid; i < 128; i += nth) bias[128 + i] = b2[i] * g2[i] + be2[i];
}

// ---------------- main kernel helpers ----------------
__device__ inline uint32_t cvt_pk_bf16(float a, float b) {
    uint32_t r;
    asm("v_cvt_pk_bf16_f32 %0, %1, %2" : "=v"(r) : "v"(a), "v"(b));
    return r;
}

union frag_u { uint32_t w[4]; bf16x8 v; };

// split 8 f32 -> hi/lo bf16x8 via packed converts (lo = a - f32(hi), exact)
__device__ inline void split8(const float* f, bf16x8* hi, bf16x8* lo) {
    frag_u H, L;
    #pragma unroll
    for (int p2 = 0; p2 < 4; ++p2) {
        float a = f[2 * p2], b = f[2 * p2 + 1];
        uint32_t h = cvt_pk_bf16(a, b);
        float ha = __uint_as_float(h << 16);
        float hb = __uint_as_float(h & 0xffff0000u);
        uint32_t l = cvt_pk_bf16(a - ha, b - hb);
        H.w[p2] = h; L.w[p2] = l;
    }
    *hi = H.v; *lo = L.v;
}

// L0/L1 (swapped): D += W * act
__device__ inline f32x16 mfma3_WA(bf16x8 wh, bf16x8 wl, bf16x8 bh, bf16x8 bl, f32x16 c) {
    c = __builtin_amdgcn_mfma_f32_32x32x16_bf16(wh, bh, c, 0, 0, 0);
    c = __builtin_amdgcn_mfma_f32_32x32x16_bf16(wl, bh, c, 0, 0, 0);
    c = __builtin_amdgcn_mfma_f32_32x32x16_bf16(wh, bl, c, 0, 0, 0);
    return c;
}
// L2 (normal): D += act * W
__device__ inline f32x16 mfma3_AW(bf16x8 ah, bf16x8 al, bf16x8 wh, bf16x8 wl, f32x16 c) {
    c = __builtin_amdgcn_mfma_f32_32x32x16_bf16(ah, wh, c, 0, 0, 0);
    c = __builtin_amdgcn_mfma_f32_32x32x16_bf16(al, wh, c, 0, 0, 0);
    c = __builtin_amdgcn_mfma_f32_32x32x16_bf16(ah, wl, c, 0, 0, 0);
    return c;
}

// relu + hi/lo split + permlane32_swap assembly of next layer's K-fragments.
__device__ inline void transition(const f32x16* acc, bf16x8* fh, bf16x8* fl) {
    #pragma unroll
    for (int mt = 0; mt < 2; ++mt) {
        uint32_t H[8], L[8];
        #pragma unroll
        for (int w = 0; w < 8; ++w) {
            float a = fmaxf(acc[mt][2 * w],     0.f);
            float b = fmaxf(acc[mt][2 * w + 1], 0.f);
            uint32_t h = cvt_pk_bf16(a, b);
            float ha = __uint_as_float(h << 16);
            float hb = __uint_as_float(h & 0xffff0000u);
            H[w] = h;
            L[w] = cvt_pk_bf16(a - ha, b - hb);
        }
        #pragma unroll
        for (int ktL = 0; ktL < 2; ++ktL) {
            uint32_t a0 = H[4 * ktL + 0], b0 = H[4 * ktL + 2];
            uint32_t a1 = H[4 * ktL + 1], b1 = H[4 * ktL + 3];
            asm("v_permlane32_swap_b32 %0, %1" : "+v"(a0), "+v"(b0));
            asm("v_permlane32_swap_b32 %0, %1" : "+v"(a1), "+v"(b1));
            uint32_t c0 = L[4 * ktL + 0], d0 = L[4 * ktL + 2];
            uint32_t c1 = L[4 * ktL + 1], d1 = L[4 * ktL + 3];
            asm("v_permlane32_swap_b32 %0, %1" : "+v"(c0), "+v"(d0));
            asm("v_permlane32_swap_b32 %0, %1" : "+v"(c1), "+v"(d1));
            frag_u F; F.w[0] = a0; F.w[1] = a1; F.w[2] = b0; F.w[3] = b1;
            frag_u G; G.w[0] = c0; G.w[1] = c1; G.w[2] = d0; G.w[3] = d1;
            fh[mt * 2 + ktL] = F.v;
            fl[mt * 2 + ktL] = G.v;
        }
    }
}

__global__ __launch_bounds__(512)
void pointnet_mfma(
    const float* __restrict__ xyz_proj,      // [B, H*W, 3]
    const float* __restrict__ points_proj,   // [B, H*W, 64]
    const float* __restrict__ xyz_sampled,   // [B, N, 3]
    const int*   __restrict__ nidx,          // [B, N, 32]
    const float* __restrict__ vmask,         // [B, N, 32, 1]
    const uint16_t* __restrict__ wf,
    float* __restrict__ out)
{
    __shared__ uint16_t slds[LDS_U16];       // exactly 64 KiB of hot weights

    // ---- cooperative fill: 64 KiB = 4096 uint4; 512 threads x 8 iters ----
    {
        const uint4* src = (const uint4*)wf;
        uint4* dst = (uint4*)slds;
        #pragma unroll
        for (int j = 0; j < 8; ++j)
            dst[threadIdx.x + j * 512] = src[threadIdx.x + j * 512];
    }
    __syncthreads();   // only barrier; waves independent afterwards

    // XCD-aware bijective swizzle (grid 4096, 8 XCDs, 512 blocks per XCD)
    const int bid = blockIdx.x;
    const int swz = (bid & 7) * 512 + (bid >> 3);

    const int t    = threadIdx.x & 63;
    const int widx = threadIdx.x >> 6;       // 0..7
    const int p    = swz * 8 + widx;          // point id in [0, 2*NN)
    const int rb   = (p >> 14) << 16;          // b * HW

    const int r  = t & 31;   // this lane's neighbor (col) all the way through
    const int kh = t >> 5;   // k-half selector

    const bf16x8* L0h = (const bf16x8*)(slds + WS_L0H);
    const bf16x8* L0l = (const bf16x8*)(slds + WS_L0L);
    const bf16x8* L1h = (const bf16x8*)(slds + WS_L1H);
    const bf16x8* L1l = (const bf16x8*)(slds + WS_L1L);
    const bf16x8* L2h = (const bf16x8*)(slds + WS_L2H);
    const bf16x8* L2l = (const bf16x8*)(slds + WS_L2L);
    const bf16x8* X0h = (const bf16x8*)(wf + WS_X0H);   // xyz step: global
    const bf16x8* X0l = (const bf16x8*)(wf + WS_X0L);
    const float*  bias = (const float*)(wf + WS_BIAS);

    // ---- per-neighbor scalars (each lane: its own neighbor) ----
    const int   idx = nidx[(size_t)p * 32 + r];
    const float m   = vmask[(size_t)p * 32 + r];
    float xd0, xd1, xd2;
    {
        const float* xs = xyz_proj + (size_t)(rb + idx) * 3;
        const float* ns = xyz_sampled + (size_t)p * 3;
        xd0 = xs[0] * m - ns[0];
        xd1 = xs[1] * m - ns[1];
        xd2 = xs[2] * m - ns[2];
    }
    const float* rowp = points_proj + (size_t)(rb + idx) * 64 + 8 * kh;

    // ---- layer 0: K = 64 (channels) + 3 (xyz) -> 64, swapped (W=A) ----
    f32x16 acc0[2];
    #pragma unroll
    for (int mt = 0; mt < 2; ++mt)
        #pragma unroll
        for (int q = 0; q < 4; ++q) {
            float4 bq = *(const float4*)(bias + mt * 32 + 4 * kh + 8 * q);
            acc0[mt][4 * q + 0] = bq.x; acc0[mt][4 * q + 1] = bq.y;
            acc0[mt][4 * q + 2] = bq.z; acc0[mt][4 * q + 3] = bq.w;
        }
    #pragma unroll
    for (int kt = 0; kt < 4; ++kt) {
        bf16x8 wh0 = L0h[(kt * 2 + 0) * 64 + t], wl0 = L0l[(kt * 2 + 0) * 64 + t];
        bf16x8 wh1 = L0h[(kt * 2 + 1) * 64 + t], wl1 = L0l[(kt * 2 + 1) * 64 + t];
        float f[8];
        *(float4*)&f[0] = ((const float4*)(rowp + kt * 16))[0];
        *(float4*)&f[4] = ((const float4*)(rowp + kt * 16))[1];
        #pragma unroll
        for (int e = 0; e < 8; ++e) f[e] *= m;
        bf16x8 bh, bl; split8(f, &bh, &bl);
        acc0[0] = mfma3_WA(wh0, wl0, bh, bl, acc0[0]);
        acc0[1] = mfma3_WA(wh1, wl1, bh, bl, acc0[1]);
    }
    {   // xyz k-step (k 64..66 live in kh==0 lanes, e<3); weights from global
        bf16x8 wh0 = X0h[0 * 64 + t], wl0 = X0l[0 * 64 + t];
        bf16x8 wh1 = X0h[1 * 64 + t], wl1 = X0l[1 * 64 + t];
        const bool lo32 = (kh == 0);
        float f[8] = { lo32 ? xd0 : 0.f, lo32 ? xd1 : 0.f, lo32 ? xd2 : 0.f,
                       0.f, 0.f, 0.f, 0.f, 0.f };
        bf16x8 bh, bl; split8(f, &bh, &bl);
        acc0[0] = mfma3_WA(wh0, wl0, bh, bl, acc0[0]);
        acc0[1] = mfma3_WA(wh1, wl1, bh, bl, acc0[1]);
    }

    // ---- transition 1: in-register relu+split+swap -> L1 B-fragments ----
    bf16x8 fh[4], fl[4];
    transition(acc0, fh, fl);

    // ---- layer 1: 64 -> 64, swapped (W=A) ----
    f32x16 acc1[2];
    #pragma unroll
    for (int mt = 0; mt < 2; ++mt)
        #pragma unroll
        for (int q = 0; q < 4; ++q) {
            float4 bq = *(const float4*)(bias + 64 + mt * 32 + 4 * kh + 8 * q);
            acc1[mt][4 * q + 0] = bq.x; acc1[mt][4 * q + 1] = bq.y;
            acc1[mt][4 * q + 2] = bq.z; acc1[mt][4 * q + 3] = bq.w;
        }
    #pragma unroll
    for (int kt = 0; kt < 4; ++kt) {
        bf16x8 wh0 = L1h[(kt * 2 + 0) * 64 + t], wl0 = L1l[(kt * 2 + 0) * 64 + t];
        bf16x8 wh1 = L1h[(kt * 2 + 1) * 64 + t], wl1 = L1l[(kt * 2 + 1) * 64 + t];
        acc1[0] = mfma3_WA(wh0, wl0, fh[kt], fl[kt], acc1[0]);
        acc1[1] = mfma3_WA(wh1, wl1, fh[kt], fl[kt], acc1[1]);
    }

    // ---- transition 2 -> L2 A-fragments (same per-lane layout) ----
    bf16x8 gh[4], gl[4];
    transition(acc1, gh, gl);

    // ---- layer 2: 64 -> 128, normal (act=A); fused maxpool + store ----
    #pragma unroll
    for (int half = 0; half < 2; ++half) {
        f32x16 acc2[2];
        const float bb0 = bias[128 + (half * 2 + 0) * 32 + r];
        const float bb1 = bias[128 + (half * 2 + 1) * 32 + r];
        #pragma unroll
        for (int i = 0; i < 16; ++i) { acc2[0][i] = bb0; acc2[1][i] = bb1; }
        #pragma unroll
        for (int kt = 0; kt < 4; ++kt) {
            bf16x8 wh0 = L2h[(kt * 4 + half * 2 + 0) * 64 + t];
            bf16x8 wl0 = L2l[(kt * 4 + half * 2 + 0) * 64 + t];
            bf16x8 wh1 = L2h[(kt * 4 + half * 2 + 1) * 64 + t];
            bf16x8 wl1 = L2l[(kt * 4 + half * 2 + 1) * 64 + t];
            acc2[0] = mfma3_AW(gh[kt], gl[kt], wh0, wl0, acc2[0]);
            acc2[1] = mfma3_AW(gh[kt], gl[kt], wh1, wl1, acc2[1]);
        }
        #pragma unroll
        for (int j = 0; j < 2; ++j) {
            float v = acc2[j][0];
            #pragma unroll
            for (int g = 1; g < 16; ++g) v = fmaxf(v, acc2[j][g]);
            v = fmaxf(v, __shfl_xor(v, 32));   // merge kh halves
            v = fmaxf(v, 0.f);                 // relu commutes with max
            // kh=0 lanes store tuple copy 0, kh=1 lanes store copy 1
            size_t o = (size_t)p * 128 + (half * 2 + j) * 32 + r
                     + (size_t)kh * OUT_HALF;
            out[o] = v;
        }
    }
}

extern "C" void kernel_launch(void* const* d_in, const int* in_sizes, int n_in,
                              void* d_out, int out_size, void* d_ws, size_t ws_size,
                              hipStream_t stream) {
    const float* xyz_proj    = (const float*)d_in[0];
    const float* points_proj = (const float*)d_in[1];
    const float* xyz_sampled = (const float*)d_in[2];
    const int*   neighbor_idx= (const int*)  d_in[3];
    const float* valid_mask  = (const float*)d_in[4];
    const float* W0 = (const float*)d_in[5];
    const float* b0 = (const float*)d_in[6];
    const float* g0 = (const float*)d_in[7];
    const float* be0= (const float*)d_in[8];
    const float* W1 = (const float*)d_in[9];
    const float* b1 = (const float*)d_in[10];
    const float* g1 = (const float*)d_in[11];
    const float* be1= (const float*)d_in[12];
    const float* W2 = (const float*)d_in[13];
    const float* b2 = (const float*)d_in[14];
    const float* g2 = (const float*)d_in[15];
    const float* be2= (const float*)d_in[16];

    uint16_t* ws = (uint16_t*)d_ws;

    prep_weights<<<64, 256, 0, stream>>>(W0, b0, g0, be0,
                                         W1, b1, g1, be1,
                                         W2, b2, g2, be2, ws);

    // 32768 points: 1 per wave, 8 waves per block -> 4096 blocks
    pointnet_mfma<<<4096, 512, 0, stream>>>(
        xyz_proj, points_proj, xyz_sampled, neighbor_idx, valid_mask,
        ws, (float*)d_out);
}